// Round 5
// baseline (870.976 us; speedup 1.0000x reference)
//
#include <hip/hip_runtime.h>
#include <hip/hip_bf16.h>
#include <cstdint>
#include <cstddef>

#define B_ 4
#define L_ 8192
#define D_ 512
#define H_ 1024
#define NC_ 256           // chunks along L for the 3-phase scan
#define LC_ (L_ / NC_)    // 32

typedef float  f32x4 __attribute__((ext_vector_type(4)));
typedef short  s16x8 __attribute__((ext_vector_type(8)));
typedef __bf16 b16x8 __attribute__((ext_vector_type(8)));

// ---- MFMA wrapper: tolerate either builtin signature (v8i16 or v8bf16) ----
template <typename T, typename U>
__device__ inline auto mfma_sel(T a, T b, f32x4 c, U, int)
    -> decltype(__builtin_amdgcn_mfma_f32_16x16x32_bf16(a, b, c, 0, 0, 0)) {
  return __builtin_amdgcn_mfma_f32_16x16x32_bf16(a, b, c, 0, 0, 0);
}
template <typename T, typename U>
__device__ inline f32x4 mfma_sel(T a, T b, f32x4 c, U, long) {
  return __builtin_amdgcn_mfma_f32_16x16x32_bf16(
      __builtin_bit_cast(U, a), __builtin_bit_cast(U, b), c, 0, 0, 0);
}
__device__ inline f32x4 mfma_bf16_16x16x32(s16x8 a, s16x8 b, f32x4 c) {
  return mfma_sel(a, b, c, b16x8{}, 0);
}

// ---- fp32 <-> bf16 ----
__device__ inline ushort f2bf(float f) {
  uint32_t u = __builtin_bit_cast(uint32_t, f);
  uint32_t r = (u + 0x7fffu + ((u >> 16) & 1u)) >> 16;
  return (ushort)r;
}
__device__ inline float bf2f(ushort u) {
  return __builtin_bit_cast(float, (uint32_t)u << 16);
}

// ---- scan math helpers ----
__device__ inline float softplus_f(float x) {
  return fmaxf(x, 0.f) + __logf(1.f + __expf(-fabsf(x)));
}
__device__ inline float logaddexp_f(float a, float b) {
  float m = fmaxf(a, b);
  return m + __logf(1.f + __expf(-fabsf(a - b)));
}
// from (hidden, gate): lc = -softplus(g); v = log_z + log_tilde_h
__device__ inline void transform_f(float hd, float g, float& lc, float& v) {
  float sp = softplus_f(g);
  lc = -sp;
  float lz = g - sp;                       // -softplus(-g)
  float lth = (hd >= 0.f) ? __logf(hd + 0.5f) : (hd - softplus_f(hd));
  v = lz + lth;
}

__global__ void cast_kernel(const float* __restrict__ in, ushort* __restrict__ out, int n4) {
  int i = blockIdx.x * blockDim.x + threadIdx.x;
  if (i >= n4) return;
  float4 f = reinterpret_cast<const float4*>(in)[i];
  ushort4 o;
  o.x = f2bf(f.x); o.y = f2bf(f.y); o.z = f2bf(f.z); o.w = f2bf(f.w);
  reinterpret_cast<ushort4*>(out)[i] = o;
}

// both weights in one launch
__global__ void cast2_kernel(const float* __restrict__ in0, ushort* __restrict__ out0, int n4_0,
                             const float* __restrict__ in1, ushort* __restrict__ out1, int n4_1) {
  int i = blockIdx.x * blockDim.x + threadIdx.x;
  const float* in; ushort* out;
  if (i < n4_0) { in = in0; out = out0; }
  else { i -= n4_0; if (i >= n4_1) return; in = in1; out = out1; }
  float4 f = reinterpret_cast<const float4*>(in)[i];
  ushort4 o;
  o.x = f2bf(f.x); o.y = f2bf(f.y); o.z = f2bf(f.z); o.w = f2bf(f.w);
  reinterpret_cast<ushort4*>(out)[i] = o;
}

#define GLDS(srcp, dstp)                                                            \
  __builtin_amdgcn_global_load_lds(                                                 \
      (const __attribute__((address_space(1))) void*)(srcp),                        \
      (__attribute__((address_space(3))) void*)(dstp), 16, 0, 0)

// barrier with full compiler memory fence (raw s_barrier; vmcnt managed manually)
#define BAR()                               \
  do {                                      \
    asm volatile("" ::: "memory");          \
    __builtin_amdgcn_s_barrier();           \
    asm volatile("" ::: "memory");          \
  } while (0)

// ---- NT GEMM: C[m][n] = sum_k A[m][k]*Bm[n][k] + bias[n]; A:MxK, Bm:NxK (row-major bf16) ----
// R5 structural change: TWO RESIDENT BLOCKS PER CU (was 1). All R1-R4 schedule variants
// pinned at MfmaUtil 27-29% because a single resident block serializes stage-waits, LDS
// bursts, barriers and (R4) the epilogue-transform VALU tail against its own MFMA. With 2
// co-resident blocks, one block's stalls overlap the other's MFMA (m114: MFMA/VALU pipes
// co-schedule fully across waves). To fit 2 blocks: BK=32, 2-deep double buffer ->
// LDS = BM*32*2*2 + 256*32*2*2 bytes (BM=256: 64 KiB; BM=128: 48 KiB), launch_bounds(512,4)
// caps VGPR at 128 (R2 measured 92 at this structure).
//
// BM x 256 tile, 8 waves (2M x 4N): per-wave BM/2 x 64 output (acc[BM/32][4]).
// Per K-step: {vmcnt(0); BAR; read frags + issue t+1 stages; BAR; MFMA} (BM=256 splits
// MFMA into two m-half phases with a pacing BAR). Barriers are correctness-minimal; the
// top vmcnt(0)+BAR makes all waves' t-tile global_load_lds visible before reads.
// Staging/swizzle = R2's verified 64B-row scheme (0 bank conflicts measured): one
// global_load_lds = 16 rows x 64B; lane l -> row l>>2, phys 16B chunk l&3, global chunk
// (l&3)^((l>>3)&3)  [phys ^ ((row>>1)&3)]; frag read chunk = quad ^ ((l15>>1)&3).
//
// MODE 0: plain fp32 output + bias (GEMM2, BM=128 so grid=512 = 2 blocks/CU exactly).
// MODE 1 (GEMM1, BM=256): fused recurrence-transform epilogue; block owns 128 channels,
// Bs rows 0..127 = hidden [n0,n0+128), rows 128..255 = gate [1024+n0,...), n0=bn/2;
// wave frag map wn0=(wave&3)*32: acc[mi][0..1]=hidden, acc[mi][2..3]=gate of same
// channels; epilogue writes lc -> C[l][ch], v -> C[l][1024+ch] (bf16).
// XCD-aware block swizzle (grids divisible by 8). setprio(1) around MFMA clusters.
template <int MODE, int BM>
__global__ __launch_bounds__(512, 4)
void gemm_bt(const ushort* __restrict__ A, const ushort* __restrict__ Bm,
             const float* __restrict__ bias, void* __restrict__ Cv,
             int M, int N, int K) {
  constexpr int MI = BM / 32;        // m-frags per wave (8 or 4)
  constexpr int nA = BM / 128;       // A staging instrs per wave (2 or 1)
  __shared__ ushort As[2][BM * 32];
  __shared__ ushort Bs[2][256 * 32];
  const int tid  = threadIdx.x;
  const int wave = tid >> 6;
  const int lane = tid & 63;
  const int l15  = lane & 15;
  const int quad = lane >> 4;

  // XCD swizzle: dispatch index d goes to XCD d%8; give each XCD a contiguous logical chunk.
  int id = blockIdx.y * gridDim.x + blockIdx.x;
  const int nwg = gridDim.x * gridDim.y;
  id = (id & 7) * (nwg >> 3) + (id >> 3);
  const int bxi = id % gridDim.x;
  const int byi = id / gridDim.x;

  const long bm = (long)byi * BM;
  const long bn = (long)bxi * 256;
  const int  wm = (wave >> 2) * (BM / 2);

  f32x4 acc[MI][4];
#pragma unroll
  for (int i = 0; i < MI; ++i)
#pragma unroll
    for (int j = 0; j < 4; ++j) acc[i][j] = (f32x4){0.f, 0.f, 0.f, 0.f};

  // staging lane map (R2-verified): row-in-group rl = lane>>2, global chunk cb.
  const int rl = lane >> 2;
  const int cb = (lane & 3) ^ ((lane >> 3) & 3);
  const ushort* gA0 = A + (bm + wave * 16 + rl) * (long)K + cb * 8;
  const ushort* gB0;
  if (MODE == 1) {
    const long n0 = bn >> 1;
    gB0 = Bm + (n0 + wave * 16 + rl) * (long)K + cb * 8;
  } else {
    gB0 = Bm + (bn + wave * 16 + rl) * (long)K + cb * 8;
  }
  const long bstep = (MODE == 1 ? 1024L : 128L) * K;   // B-tile high-half source offset

  // fragment-read swizzled chunk offset (ushort units)
  const int sq = (quad ^ ((l15 >> 1) & 3)) * 8;
  int arow[MI], brow[4];
#pragma unroll
  for (int i = 0; i < MI; ++i) arow[i] = (wm + i * 16 + l15) * 32;
  if (MODE == 1) {
    const int wn0 = (wave & 3) * 32;   // 32 channels per wave; j<2 hidden, j>=2 gate
#pragma unroll
    for (int j = 0; j < 4; ++j) {
      const int trow = (j < 2) ? (wn0 + j * 16) : (128 + wn0 + (j - 2) * 16);
      brow[j] = (trow + l15) * 32;
    }
  } else {
    const int wn = (wave & 3) * 64;
#pragma unroll
    for (int j = 0; j < 4; ++j) brow[j] = (wn + j * 16 + l15) * 32;
  }

  const int nkt = K >> 5;

  // prologue: stage K-step 0 -> buf 0 (nA + 2 loads per wave)
#pragma unroll
  for (int i = 0; i < nA; ++i)
    GLDS(gA0 + (128L * i) * K, &As[0][(wave * 16 + 128 * i) * 32]);
  GLDS(gB0,         &Bs[0][(wave * 16) * 32]);
  GLDS(gB0 + bstep, &Bs[0][(wave * 16 + 128) * 32]);

  for (int t = 0; t < nkt; ++t) {
    // drain tile t's loads (issued during t-1 / prologue), then make them visible
    asm volatile("s_waitcnt vmcnt(0)" ::: "memory");
    BAR();

    const int buf  = t & 1;
    const int nbuf = buf ^ 1;
    const bool pf  = (t + 1) < nkt;
    const ushort* Ac = As[buf];
    const ushort* Bc = Bs[buf];
    const long koff = (long)(t + 1) * 32;
    s16x8 bf[4], af[4];

    // ---- phase 1: read B frags + low A frags; issue A(t+1) ----
#pragma unroll
    for (int j = 0; j < 4; ++j)
      bf[j] = *reinterpret_cast<const s16x8*>(&Bc[brow[j] + sq]);
#pragma unroll
    for (int i = 0; i < (MI < 4 ? MI : 4); ++i)
      af[i] = *reinterpret_cast<const s16x8*>(&Ac[arow[i] + sq]);
    if (pf) {
      // WAR safe: nbuf holds tile t-1, fully read before this iteration's top barrier.
#pragma unroll
      for (int i = 0; i < nA; ++i)
        GLDS(gA0 + (128L * i) * K + koff, &As[nbuf][(wave * 16 + 128 * i) * 32]);
      if (MI == 4) {   // single-phase variant: also issue B here
        GLDS(gB0 + koff,         &Bs[nbuf][(wave * 16) * 32]);
        GLDS(gB0 + bstep + koff, &Bs[nbuf][(wave * 16 + 128) * 32]);
      }
    }
    BAR();
    __builtin_amdgcn_s_setprio(1);
#pragma unroll
    for (int i = 0; i < (MI < 4 ? MI : 4); ++i)
#pragma unroll
      for (int j = 0; j < 4; ++j)
        acc[i][j] = mfma_bf16_16x16x32(af[i], bf[j], acc[i][j]);
    __builtin_amdgcn_s_setprio(0);

    if (MI == 8) {
      // ---- phase 2: high A frags; issue B(t+1) ----
#pragma unroll
      for (int i = 0; i < 4; ++i)
        af[i] = *reinterpret_cast<const s16x8*>(&Ac[arow[4 + i] + sq]);
      if (pf) {
        GLDS(gB0 + koff,         &Bs[nbuf][(wave * 16) * 32]);
        GLDS(gB0 + bstep + koff, &Bs[nbuf][(wave * 16 + 128) * 32]);
      }
      BAR();
      __builtin_amdgcn_s_setprio(1);
#pragma unroll
      for (int i = 0; i < 4; ++i)
#pragma unroll
        for (int j = 0; j < 4; ++j)
          acc[4 + i][j] = mfma_bf16_16x16x32(af[i], bf[j], acc[4 + i][j]);
      __builtin_amdgcn_s_setprio(0);
    }
  }

  // epilogue: C/D layout col = lane&15, row = quad*4 + reg
  if (MODE == 1) {
    const long n0  = bn >> 1;
    const int  wn0 = (wave & 3) * 32;
#pragma unroll
    for (int mi = 0; mi < MI; ++mi) {
      const long mrow = bm + wm + mi * 16 + quad * 4;
#pragma unroll
      for (int j = 0; j < 2; ++j) {
        const long ch = n0 + wn0 + j * 16 + l15;
        const float bh = bias[ch];
        const float bg = bias[(long)(N >> 1) + ch];   // gate bias (N/2 = H)
        ushort* lp = (ushort*)Cv + mrow * (long)N + ch;
#pragma unroll
        for (int r = 0; r < 4; ++r) {
          float hd = acc[mi][j][r] + bh;
          float g  = acc[mi][j + 2][r] + bg;
          float lc, v; transform_f(hd, g, lc, v);
          lp[(long)r * N] = f2bf(lc);
          lp[(long)r * N + (N >> 1)] = f2bf(v);
        }
      }
    }
  } else {
    const int wn = (wave & 3) * 64;
#pragma unroll
    for (int mi = 0; mi < MI; ++mi) {
      const long mrow = bm + wm + mi * 16 + quad * 4;
#pragma unroll
      for (int ni = 0; ni < 4; ++ni) {
        const long ncol = bn + wn + ni * 16 + l15;
        const float bv = bias[ncol];
        float* cp = (float*)Cv + mrow * (long)N + ncol;
#pragma unroll
        for (int r = 0; r < 4; ++r) cp[(long)r * N] = acc[mi][ni][r] + bv;
      }
    }
  }
}

// phase 1: per (b, chunk, h-quad) compose chunk (Asum, Bv) for 4 channels.
// hg holds (lc, v) precomputed by GEMM1's epilogue: lc at col ch, v at col 1024+ch.
__global__ void scan_phase1(const ushort* __restrict__ hg,
                            float* __restrict__ Ac, float* __restrict__ Bc) {
  int gid = blockIdx.x * blockDim.x + threadIdx.x;  // B_*NC_*H_/4
  int hq = gid & (H_ / 4 - 1);       // h/4, 0..255
  int c  = (gid >> 8) & (NC_ - 1);
  int b  = gid >> 16;
  const ushort* p = hg + ((size_t)(b * L_ + c * LC_) * (2 * H_)) + hq * 4;
  float As[4] = {0.f, 0.f, 0.f, 0.f};
  float Bv[4] = {-INFINITY, -INFINITY, -INFINITY, -INFINITY};
#pragma unroll 4
  for (int l = 0; l < LC_; ++l) {
    ushort4 lc4 = *reinterpret_cast<const ushort4*>(p);
    ushort4 v4  = *reinterpret_cast<const ushort4*>(p + H_);
    float lcv[4] = {bf2f(lc4.x), bf2f(lc4.y), bf2f(lc4.z), bf2f(lc4.w)};
    float vv[4]  = {bf2f(v4.x),  bf2f(v4.y),  bf2f(v4.z),  bf2f(v4.w)};
#pragma unroll
    for (int j = 0; j < 4; ++j) {
      As[j] += lcv[j];
      Bv[j] = logaddexp_f(Bv[j] + lcv[j], vv[j]);
    }
    p += 2 * H_;
  }
  size_t o = (size_t)(b * NC_ + c) * H_ + hq * 4;
  *reinterpret_cast<float4*>(&Ac[o]) = make_float4(As[0], As[1], As[2], As[3]);
  *reinterpret_cast<float4*>(&Bc[o]) = make_float4(Bv[0], Bv[1], Bv[2], Bv[3]);
}

// phase 2: per (b, h) exclusive scan over chunk summaries -> carry (incoming log_h per chunk)
__global__ void scan_phase2(const float* __restrict__ Ac, const float* __restrict__ Bc,
                            float* __restrict__ carry) {
  int gid = blockIdx.x * blockDim.x + threadIdx.x;  // B_*H_
  int h = gid & (H_ - 1);
  int b = gid >> 10;
  float P = -INFINITY;
  for (int c = 0; c < NC_; ++c) {
    size_t o = (size_t)(b * NC_ + c) * H_ + h;
    carry[o] = P;
    P = logaddexp_f(P + Ac[o], Bc[o]);
  }
}

// phase 3: re-scan chunk with carry, emit h = exp(log_h) as bf16 (4 channels/thread)
__global__ void scan_phase3(const ushort* __restrict__ hg, const float* __restrict__ carry,
                            ushort* __restrict__ hb) {
  int gid = blockIdx.x * blockDim.x + threadIdx.x;  // B_*NC_*H_/4
  int hq = gid & (H_ / 4 - 1);
  int c  = (gid >> 8) & (NC_ - 1);
  int b  = gid >> 16;
  float4 cr = *reinterpret_cast<const float4*>(&carry[(size_t)(b * NC_ + c) * H_ + hq * 4]);
  float lh[4] = {cr.x, cr.y, cr.z, cr.w};
  const ushort* p = hg + ((size_t)(b * L_ + c * LC_) * (2 * H_)) + hq * 4;
  ushort* q = hb + (size_t)(b * L_ + c * LC_) * H_ + hq * 4;
#pragma unroll 4
  for (int l = 0; l < LC_; ++l) {
    ushort4 lc4 = *reinterpret_cast<const ushort4*>(p);
    ushort4 v4  = *reinterpret_cast<const ushort4*>(p + H_);
    float lcv[4] = {bf2f(lc4.x), bf2f(lc4.y), bf2f(lc4.z), bf2f(lc4.w)};
    float vv[4]  = {bf2f(v4.x),  bf2f(v4.y),  bf2f(v4.z),  bf2f(v4.w)};
    ushort4 o;
    ushort* op = &o.x;
#pragma unroll
    for (int j = 0; j < 4; ++j) {
      lh[j] = logaddexp_f(lh[j] + lcv[j], vv[j]);
      op[j] = f2bf(__expf(lh[j]));
    }
    *reinterpret_cast<ushort4*>(q) = o;
    p += 2 * H_;
    q += H_;
  }
}

extern "C" void kernel_launch(void* const* d_in, const int* in_sizes, int n_in,
                              void* d_out, int out_size, void* d_ws, size_t ws_size,
                              hipStream_t stream) {
  const float* x     = (const float*)d_in[0];
  const float* W_in  = (const float*)d_in[1];
  const float* b_in  = (const float*)d_in[2];
  const float* W_out = (const float*)d_in[3];
  const float* b_out = (const float*)d_in[4];
  float* out = (float*)d_out;

  char* ws = (char*)d_ws;
  size_t off = 0;
  auto alloc = [&](size_t bytes) {
    void* p = ws + off;
    off = (off + bytes + 255) & ~(size_t)255;
    return p;
  };
  // region shared by xb (alive: cast -> GEMM1) and hb (alive: phase3 -> GEMM2)
  ushort* xb    = (ushort*)alloc((size_t)B_ * L_ * H_ * 2);       // 67 MB (union)
  ushort* hb    = xb;
  ushort* Wib   = (ushort*)alloc((size_t)2 * H_ * D_ * 2);        // 2 MB
  ushort* Wob   = (ushort*)alloc((size_t)D_ * H_ * 2);            // 1 MB
  ushort* hgb   = (ushort*)alloc((size_t)B_ * L_ * 2 * H_ * 2);   // 134 MB (bf16: lc, v)
  float*  Ac    = (float*)alloc((size_t)B_ * NC_ * H_ * 4);       // 4 MB
  float*  Bc    = (float*)alloc((size_t)B_ * NC_ * H_ * 4);       // 4 MB
  float*  carry = (float*)alloc((size_t)B_ * NC_ * H_ * 4);       // 4 MB
  // total ~216 MB

  // casts to bf16
  cast_kernel<<<(B_ * L_ * D_ / 4 + 255) / 256, 256, 0, stream>>>(x, xb, B_ * L_ * D_ / 4);
  {
    int n0 = 2 * H_ * D_ / 4, n1 = D_ * H_ / 4;
    cast2_kernel<<<(n0 + n1 + 255) / 256, 256, 0, stream>>>(W_in, Wib, n0, W_out, Wob, n1);
  }

  // GEMM1: (lc, v) = transform(x . W_in^T + b_in)   (M=32768, N=2048, K=512), bf16 out
  gemm_bt<1, 256><<<dim3((2 * H_) / 256, (B_ * L_) / 256), 512, 0, stream>>>(
      xb, Wib, b_in, hgb, B_ * L_, 2 * H_, D_);

  // chunked scan along L (4 channels per thread)
  scan_phase1<<<(B_ * NC_ * H_ / 4) / 256, 256, 0, stream>>>(hgb, Ac, Bc);
  scan_phase2<<<(B_ * H_) / 256, 256, 0, stream>>>(Ac, Bc, carry);
  scan_phase3<<<(B_ * NC_ * H_ / 4) / 256, 256, 0, stream>>>(hgb, carry, hb);

  // GEMM2: out = h . W_out^T + b_out   (M=32768, N=512, K=1024), fp32 out
  // BM=128 -> grid = 512 blocks = exactly 2 resident blocks per CU.
  gemm_bt<0, 128><<<dim3(D_ / 256, (B_ * L_) / 128), 512, 0, stream>>>(
      hb, Wob, b_out, out, B_ * L_, D_, H_);
}

// Round 6
// 367.937 us; speedup vs baseline: 2.3672x; 2.3672x over previous
//
#include <hip/hip_runtime.h>
#include <hip/hip_bf16.h>
#include <cstdint>
#include <cstddef>

#define B_ 4
#define L_ 8192
#define D_ 512
#define H_ 1024
#define NC_ 256           // chunks along L for the 3-phase scan
#define LC_ (L_ / NC_)    // 32

typedef float  f32x4 __attribute__((ext_vector_type(4)));
typedef short  s16x8 __attribute__((ext_vector_type(8)));
typedef __bf16 b16x8 __attribute__((ext_vector_type(8)));

// ---- MFMA wrapper: tolerate either builtin signature (v8i16 or v8bf16) ----
template <typename T, typename U>
__device__ inline auto mfma_sel(T a, T b, f32x4 c, U, int)
    -> decltype(__builtin_amdgcn_mfma_f32_16x16x32_bf16(a, b, c, 0, 0, 0)) {
  return __builtin_amdgcn_mfma_f32_16x16x32_bf16(a, b, c, 0, 0, 0);
}
template <typename T, typename U>
__device__ inline f32x4 mfma_sel(T a, T b, f32x4 c, U, long) {
  return __builtin_amdgcn_mfma_f32_16x16x32_bf16(
      __builtin_bit_cast(U, a), __builtin_bit_cast(U, b), c, 0, 0, 0);
}
__device__ inline f32x4 mfma_bf16_16x16x32(s16x8 a, s16x8 b, f32x4 c) {
  return mfma_sel(a, b, c, b16x8{}, 0);
}

// ---- fp32 <-> bf16 ----
__device__ inline ushort f2bf(float f) {
  uint32_t u = __builtin_bit_cast(uint32_t, f);
  uint32_t r = (u + 0x7fffu + ((u >> 16) & 1u)) >> 16;
  return (ushort)r;
}
__device__ inline float bf2f(ushort u) {
  return __builtin_bit_cast(float, (uint32_t)u << 16);
}

// ---- scan math helpers ----
__device__ inline float softplus_f(float x) {
  return fmaxf(x, 0.f) + __logf(1.f + __expf(-fabsf(x)));
}
__device__ inline float logaddexp_f(float a, float b) {
  float m = fmaxf(a, b);
  return m + __logf(1.f + __expf(-fabsf(a - b)));
}
// from (hidden, gate): lc = -softplus(g); v = log_z + log_tilde_h
__device__ inline void transform_f(float hd, float g, float& lc, float& v) {
  float sp = softplus_f(g);
  lc = -sp;
  float lz = g - sp;                       // -softplus(-g)
  float lth = (hd >= 0.f) ? __logf(hd + 0.5f) : (hd - softplus_f(hd));
  v = lz + lth;
}

__global__ void cast_kernel(const float* __restrict__ in, ushort* __restrict__ out, int n4) {
  int i = blockIdx.x * blockDim.x + threadIdx.x;
  if (i >= n4) return;
  float4 f = reinterpret_cast<const float4*>(in)[i];
  ushort4 o;
  o.x = f2bf(f.x); o.y = f2bf(f.y); o.z = f2bf(f.z); o.w = f2bf(f.w);
  reinterpret_cast<ushort4*>(out)[i] = o;
}

// both weights in one launch
__global__ void cast2_kernel(const float* __restrict__ in0, ushort* __restrict__ out0, int n4_0,
                             const float* __restrict__ in1, ushort* __restrict__ out1, int n4_1) {
  int i = blockIdx.x * blockDim.x + threadIdx.x;
  const float* in; ushort* out;
  if (i < n4_0) { in = in0; out = out0; }
  else { i -= n4_0; if (i >= n4_1) return; in = in1; out = out1; }
  float4 f = reinterpret_cast<const float4*>(in)[i];
  ushort4 o;
  o.x = f2bf(f.x); o.y = f2bf(f.y); o.z = f2bf(f.z); o.w = f2bf(f.w);
  reinterpret_cast<ushort4*>(out)[i] = o;
}

#define GLDS(srcp, dstp)                                                            \
  __builtin_amdgcn_global_load_lds(                                                 \
      (const __attribute__((address_space(1))) void*)(srcp),                        \
      (__attribute__((address_space(3))) void*)(dstp), 16, 0, 0)

// ---- NT GEMM: C[m][n] = sum_k A[m][k]*Bm[n][k] + bias[n]; A:MxK, Bm:NxK (row-major bf16) ----
// R6: revert R5's spill disaster (launch_bounds(512,4) capped VGPR at 128 < acc's 128 ->
// scratch: WRITE 131MB->2GB, MfmaUtil 4%). Residency retried SPILL-FREE via the m97-proven
// geometry: 128x128 tile, 256 threads / 4 waves (2x2), BK=64, 32 KiB single-buffered LDS,
// acc[4][4] = 64 VGPR (R0 measured 92 total). launch_bounds(256,3) caps VGPR ~170 (ample)
// and allows 4-5 resident blocks/CU -> cross-block MFMA/VALU/barrier overlap (m114), which
// also absorbs the MODE-1 transform epilogue tail.
//
// K-loop = R0's verified 2-barrier structure: {8x global_load_lds; __syncthreads (drains
// vmcnt); 2 k-halves x 16 MFMA; __syncthreads}. LDS swizzle (128B rows, 8x16B chunks):
// phys chunk p of row r holds logical chunk p^(r&7); staging lane (rl=lane>>3, slot=lane&7)
// fetches global chunk slot^rl; frag read uses (kh*4+quad)^(l15&7). 0 conflicts R0-R4.
//
// MODE 0: fp32 out + bias. MODE 1 (GEMM1): block owns 64 CHANNELS (both halves):
// Bs rows 0..63 = hidden [n0,n0+64), rows 64..127 = gate [1024+n0,...), n0 = bxi*64;
// waves 0,1 stage hidden rows, waves 2,3 gate rows. Wave frag map wn0=(wave&1)*32:
// acc[mi][0..1]=hidden, acc[mi][2..3]=gate of the same channels (lane-local pairing).
// Epilogue: lc -> C[l][ch], v -> C[l][1024+ch] (bf16), N=2048 stride.
// XCD-aware block swizzle (grids 4096 / 1024, both %8==0). setprio(1) around MFMA.
template <int MODE>
__global__ __launch_bounds__(256, 3)
void gemm_bt(const ushort* __restrict__ A, const ushort* __restrict__ Bm,
             const float* __restrict__ bias, void* __restrict__ Cv,
             int M, int N, int K) {
  __shared__ ushort As[128 * 64];
  __shared__ ushort Bs[128 * 64];
  const int tid  = threadIdx.x;
  const int wave = tid >> 6;
  const int lane = tid & 63;
  const int l15  = lane & 15;
  const int quad = lane >> 4;

  // XCD swizzle: dispatch index d goes to XCD d%8; give each XCD a contiguous logical chunk.
  int id = blockIdx.y * gridDim.x + blockIdx.x;
  const int nwg = gridDim.x * gridDim.y;
  id = (id & 7) * (nwg >> 3) + (id >> 3);
  const int bxi = id % gridDim.x;
  const int byi = id / gridDim.x;

  const long bm = (long)byi * 128;
  const int  wm = (wave >> 1) * 64;

  f32x4 acc[4][4];
#pragma unroll
  for (int i = 0; i < 4; ++i)
#pragma unroll
    for (int j = 0; j < 4; ++j) acc[i][j] = (f32x4){0.f, 0.f, 0.f, 0.f};

  // staging: wave fills rows [wave*32, wave*32+32); each instr covers 8 rows (64 lanes x 16B).
  const int rl  = lane >> 3;
  const int cb  = (lane & 7) ^ rl;
  const ushort* gA0 = A + (bm + wave * 32 + rl) * (long)K + cb * 8;
  long bRowBase;
  if (MODE == 1) {
    const long n0 = (long)bxi * 64;
    bRowBase = (wave < 2) ? (n0 + wave * 32) : (1024 + n0 + (wave - 2) * 32);
  } else {
    bRowBase = (long)bxi * 128 + wave * 32;
  }
  const ushort* gB0 = Bm + (bRowBase + rl) * (long)K + cb * 8;
  ushort* lA[4]; ushort* lB[4];
#pragma unroll
  for (int i = 0; i < 4; ++i) {
    lA[i] = &As[(wave * 32 + 8 * i) * 64];
    lB[i] = &Bs[(wave * 32 + 8 * i) * 64];
  }

  // fragment-read swizzled slot offsets: (kh*4+quad) ^ (l15&7)
  const int sq0 = ((0 * 4 + quad) ^ (l15 & 7)) * 8;
  const int sq1 = ((1 * 4 + quad) ^ (l15 & 7)) * 8;
  int arow[4], brow[4];
#pragma unroll
  for (int i = 0; i < 4; ++i) arow[i] = (wm + i * 16 + l15) * 64;
  if (MODE == 1) {
    const int wn0 = (wave & 1) * 32;   // 32 channels per wave; j<2 hidden, j>=2 gate
#pragma unroll
    for (int j = 0; j < 4; ++j) {
      const int trow = (j < 2) ? (wn0 + j * 16) : (64 + wn0 + (j - 2) * 16);
      brow[j] = (trow + l15) * 64;
    }
  } else {
    const int wn = (wave & 1) * 64;
#pragma unroll
    for (int j = 0; j < 4; ++j) brow[j] = (wn + j * 16 + l15) * 64;
  }

  for (int k0 = 0; k0 < K; k0 += 64) {
#pragma unroll
    for (int i = 0; i < 4; ++i)
      GLDS(gA0 + 8L * i * K + k0, lA[i]);
#pragma unroll
    for (int i = 0; i < 4; ++i)
      GLDS(gB0 + 8L * i * K + k0, lB[i]);
    __syncthreads();   // drains vmcnt -> LDS tile ready

#pragma unroll
    for (int kh = 0; kh < 2; ++kh) {
      const int sq = kh ? sq1 : sq0;
      s16x8 af[4], bf[4];
#pragma unroll
      for (int mi = 0; mi < 4; ++mi)
        af[mi] = *reinterpret_cast<const s16x8*>(&As[arow[mi] + sq]);
#pragma unroll
      for (int ni = 0; ni < 4; ++ni)
        bf[ni] = *reinterpret_cast<const s16x8*>(&Bs[brow[ni] + sq]);
      __builtin_amdgcn_s_setprio(1);
#pragma unroll
      for (int mi = 0; mi < 4; ++mi)
#pragma unroll
        for (int ni = 0; ni < 4; ++ni)
          acc[mi][ni] = mfma_bf16_16x16x32(af[mi], bf[ni], acc[mi][ni]);
      __builtin_amdgcn_s_setprio(0);
    }
    __syncthreads();   // protect LDS before next stage
  }

  // epilogue: C/D layout col = lane&15, row = quad*4 + reg
  if (MODE == 1) {
    const long n0  = (long)bxi * 64;
    const int  wn0 = (wave & 1) * 32;
#pragma unroll
    for (int mi = 0; mi < 4; ++mi) {
      const long mrow = bm + wm + mi * 16 + quad * 4;
#pragma unroll
      for (int j = 0; j < 2; ++j) {
        const long ch = n0 + wn0 + j * 16 + l15;
        const float bh = bias[ch];
        const float bg = bias[1024 + ch];
        ushort* lp = (ushort*)Cv + mrow * (long)N + ch;
#pragma unroll
        for (int r = 0; r < 4; ++r) {
          float hd = acc[mi][j][r] + bh;
          float g  = acc[mi][j + 2][r] + bg;
          float lc, v; transform_f(hd, g, lc, v);
          lp[(long)r * N] = f2bf(lc);
          lp[(long)r * N + 1024] = f2bf(v);
        }
      }
    }
  } else {
    const int wn = (wave & 1) * 64;
#pragma unroll
    for (int mi = 0; mi < 4; ++mi) {
      const long mrow = bm + wm + mi * 16 + quad * 4;
#pragma unroll
      for (int ni = 0; ni < 4; ++ni) {
        const long ncol = (long)bxi * 128 + wn + ni * 16 + l15;
        const float bv = bias[ncol];
        float* cp = (float*)Cv + mrow * (long)N + ncol;
#pragma unroll
        for (int r = 0; r < 4; ++r) cp[(long)r * N] = acc[mi][ni][r] + bv;
      }
    }
  }
}

// phase 1: per (b, chunk, h-quad) compose chunk (Asum, Bv) for 4 channels.
// hg holds (lc, v) precomputed by GEMM1's epilogue: lc at col ch, v at col 1024+ch.
__global__ void scan_phase1(const ushort* __restrict__ hg,
                            float* __restrict__ Ac, float* __restrict__ Bc) {
  int gid = blockIdx.x * blockDim.x + threadIdx.x;  // B_*NC_*H_/4
  int hq = gid & (H_ / 4 - 1);       // h/4, 0..255
  int c  = (gid >> 8) & (NC_ - 1);
  int b  = gid >> 16;
  const ushort* p = hg + ((size_t)(b * L_ + c * LC_) * (2 * H_)) + hq * 4;
  float As[4] = {0.f, 0.f, 0.f, 0.f};
  float Bv[4] = {-INFINITY, -INFINITY, -INFINITY, -INFINITY};
#pragma unroll 4
  for (int l = 0; l < LC_; ++l) {
    ushort4 lc4 = *reinterpret_cast<const ushort4*>(p);
    ushort4 v4  = *reinterpret_cast<const ushort4*>(p + H_);
    float lcv[4] = {bf2f(lc4.x), bf2f(lc4.y), bf2f(lc4.z), bf2f(lc4.w)};
    float vv[4]  = {bf2f(v4.x),  bf2f(v4.y),  bf2f(v4.z),  bf2f(v4.w)};
#pragma unroll
    for (int j = 0; j < 4; ++j) {
      As[j] += lcv[j];
      Bv[j] = logaddexp_f(Bv[j] + lcv[j], vv[j]);
    }
    p += 2 * H_;
  }
  size_t o = (size_t)(b * NC_ + c) * H_ + hq * 4;
  *reinterpret_cast<float4*>(&Ac[o]) = make_float4(As[0], As[1], As[2], As[3]);
  *reinterpret_cast<float4*>(&Bc[o]) = make_float4(Bv[0], Bv[1], Bv[2], Bv[3]);
}

// phase 2: per (b, h) exclusive scan over chunk summaries -> carry (incoming log_h per chunk)
__global__ void scan_phase2(const float* __restrict__ Ac, const float* __restrict__ Bc,
                            float* __restrict__ carry) {
  int gid = blockIdx.x * blockDim.x + threadIdx.x;  // B_*H_
  int h = gid & (H_ - 1);
  int b = gid >> 10;
  float P = -INFINITY;
  for (int c = 0; c < NC_; ++c) {
    size_t o = (size_t)(b * NC_ + c) * H_ + h;
    carry[o] = P;
    P = logaddexp_f(P + Ac[o], Bc[o]);
  }
}

// phase 3: re-scan chunk with carry, emit h = exp(log_h) as bf16 (4 channels/thread)
__global__ void scan_phase3(const ushort* __restrict__ hg, const float* __restrict__ carry,
                            ushort* __restrict__ hb) {
  int gid = blockIdx.x * blockDim.x + threadIdx.x;  // B_*NC_*H_/4
  int hq = gid & (H_ / 4 - 1);
  int c  = (gid >> 8) & (NC_ - 1);
  int b  = gid >> 16;
  float4 cr = *reinterpret_cast<const float4*>(&carry[(size_t)(b * NC_ + c) * H_ + hq * 4]);
  float lh[4] = {cr.x, cr.y, cr.z, cr.w};
  const ushort* p = hg + ((size_t)(b * L_ + c * LC_) * (2 * H_)) + hq * 4;
  ushort* q = hb + (size_t)(b * L_ + c * LC_) * H_ + hq * 4;
#pragma unroll 4
  for (int l = 0; l < LC_; ++l) {
    ushort4 lc4 = *reinterpret_cast<const ushort4*>(p);
    ushort4 v4  = *reinterpret_cast<const ushort4*>(p + H_);
    float lcv[4] = {bf2f(lc4.x), bf2f(lc4.y), bf2f(lc4.z), bf2f(lc4.w)};
    float vv[4]  = {bf2f(v4.x),  bf2f(v4.y),  bf2f(v4.z),  bf2f(v4.w)};
    ushort4 o;
    ushort* op = &o.x;
#pragma unroll
    for (int j = 0; j < 4; ++j) {
      lh[j] = logaddexp_f(lh[j] + lcv[j], vv[j]);
      op[j] = f2bf(__expf(lh[j]));
    }
    *reinterpret_cast<ushort4*>(q) = o;
    p += 2 * H_;
    q += H_;
  }
}

extern "C" void kernel_launch(void* const* d_in, const int* in_sizes, int n_in,
                              void* d_out, int out_size, void* d_ws, size_t ws_size,
                              hipStream_t stream) {
  const float* x     = (const float*)d_in[0];
  const float* W_in  = (const float*)d_in[1];
  const float* b_in  = (const float*)d_in[2];
  const float* W_out = (const float*)d_in[3];
  const float* b_out = (const float*)d_in[4];
  float* out = (float*)d_out;

  char* ws = (char*)d_ws;
  size_t off = 0;
  auto alloc = [&](size_t bytes) {
    void* p = ws + off;
    off = (off + bytes + 255) & ~(size_t)255;
    return p;
  };
  // region shared by xb (alive: cast -> GEMM1) and hb (alive: phase3 -> GEMM2)
  ushort* xb    = (ushort*)alloc((size_t)B_ * L_ * H_ * 2);       // 67 MB (union)
  ushort* hb    = xb;
  ushort* Wib   = (ushort*)alloc((size_t)2 * H_ * D_ * 2);        // 2 MB
  ushort* Wob   = (ushort*)alloc((size_t)D_ * H_ * 2);            // 1 MB
  ushort* hgb   = (ushort*)alloc((size_t)B_ * L_ * 2 * H_ * 2);   // 134 MB (bf16: lc, v)
  float*  Ac    = (float*)alloc((size_t)B_ * NC_ * H_ * 4);       // 4 MB
  float*  Bc    = (float*)alloc((size_t)B_ * NC_ * H_ * 4);       // 4 MB
  float*  carry = (float*)alloc((size_t)B_ * NC_ * H_ * 4);       // 4 MB
  // total ~216 MB

  // casts to bf16
  cast_kernel<<<(B_ * L_ * D_ / 4 + 255) / 256, 256, 0, stream>>>(x, xb, B_ * L_ * D_ / 4);
  {
    int n0 = 2 * H_ * D_ / 4, n1 = D_ * H_ / 4;
    cast2_kernel<<<(n0 + n1 + 255) / 256, 256, 0, stream>>>(W_in, Wib, n0, W_out, Wob, n1);
  }

  // GEMM1: (lc, v) = transform(x . W_in^T + b_in)   (M=32768, channels=1024, K=512)
  // grid.x = 1024 channels / 64 per block = 16; grid = 4096 blocks.
  gemm_bt<1><<<dim3(16, (B_ * L_) / 128), 256, 0, stream>>>(
      xb, Wib, b_in, hgb, B_ * L_, 2 * H_, D_);

  // chunked scan along L (4 channels per thread)
  scan_phase1<<<(B_ * NC_ * H_ / 4) / 256, 256, 0, stream>>>(hgb, Ac, Bc);
  scan_phase2<<<(B_ * H_) / 256, 256, 0, stream>>>(Ac, Bc, carry);
  scan_phase3<<<(B_ * NC_ * H_ / 4) / 256, 256, 0, stream>>>(hgb, carry, hb);

  // GEMM2: out = h . W_out^T + b_out   (M=32768, N=512, K=1024), fp32 out
  // grid = 4 x 256 = 1024 blocks.
  gemm_bt<0><<<dim3(D_ / 128, (B_ * L_) / 128), 256, 0, stream>>>(
      hb, Wob, b_out, out, B_ * L_, D_, H_);
}

// Round 7
// 365.621 us; speedup vs baseline: 2.3822x; 1.0063x over previous
//
#include <hip/hip_runtime.h>
#include <hip/hip_bf16.h>
#include <cstdint>
#include <cstddef>

#define B_ 4
#define L_ 8192
#define D_ 512
#define H_ 1024
#define NC_ 256           // chunks along L for the 3-phase scan
#define LC_ (L_ / NC_)    // 32

typedef float  f32x4 __attribute__((ext_vector_type(4)));
typedef short  s16x8 __attribute__((ext_vector_type(8)));
typedef __bf16 b16x8 __attribute__((ext_vector_type(8)));

// ---- MFMA wrapper: tolerate either builtin signature (v8i16 or v8bf16) ----
template <typename T, typename U>
__device__ inline auto mfma_sel(T a, T b, f32x4 c, U, int)
    -> decltype(__builtin_amdgcn_mfma_f32_16x16x32_bf16(a, b, c, 0, 0, 0)) {
  return __builtin_amdgcn_mfma_f32_16x16x32_bf16(a, b, c, 0, 0, 0);
}
template <typename T, typename U>
__device__ inline f32x4 mfma_sel(T a, T b, f32x4 c, U, long) {
  return __builtin_amdgcn_mfma_f32_16x16x32_bf16(
      __builtin_bit_cast(U, a), __builtin_bit_cast(U, b), c, 0, 0, 0);
}
__device__ inline f32x4 mfma_bf16_16x16x32(s16x8 a, s16x8 b, f32x4 c) {
  return mfma_sel(a, b, c, b16x8{}, 0);
}

// ---- fp32 <-> bf16 ----
__device__ inline ushort f2bf(float f) {
  uint32_t u = __builtin_bit_cast(uint32_t, f);
  uint32_t r = (u + 0x7fffu + ((u >> 16) & 1u)) >> 16;
  return (ushort)r;
}
__device__ inline float bf2f(ushort u) {
  return __builtin_bit_cast(float, (uint32_t)u << 16);
}

// ---- scan math helpers ----
__device__ inline float softplus_f(float x) {
  return fmaxf(x, 0.f) + __logf(1.f + __expf(-fabsf(x)));
}
__device__ inline float logaddexp_f(float a, float b) {
  float m = fmaxf(a, b);
  return m + __logf(1.f + __expf(-fabsf(a - b)));
}
// from (hidden, gate): lc = -softplus(g); v = log_z + log_tilde_h
__device__ inline void transform_f(float hd, float g, float& lc, float& v) {
  float sp = softplus_f(g);
  lc = -sp;
  float lz = g - sp;                       // -softplus(-g)
  float lth = (hd >= 0.f) ? __logf(hd + 0.5f) : (hd - softplus_f(hd));
  v = lz + lth;
}

__global__ void cast_kernel(const float* __restrict__ in, ushort* __restrict__ out, int n4) {
  int i = blockIdx.x * blockDim.x + threadIdx.x;
  if (i >= n4) return;
  float4 f = reinterpret_cast<const float4*>(in)[i];
  ushort4 o;
  o.x = f2bf(f.x); o.y = f2bf(f.y); o.z = f2bf(f.z); o.w = f2bf(f.w);
  reinterpret_cast<ushort4*>(out)[i] = o;
}

// both weights in one launch
__global__ void cast2_kernel(const float* __restrict__ in0, ushort* __restrict__ out0, int n4_0,
                             const float* __restrict__ in1, ushort* __restrict__ out1, int n4_1) {
  int i = blockIdx.x * blockDim.x + threadIdx.x;
  const float* in; ushort* out;
  if (i < n4_0) { in = in0; out = out0; }
  else { i -= n4_0; if (i >= n4_1) return; in = in1; out = out1; }
  float4 f = reinterpret_cast<const float4*>(in)[i];
  ushort4 o;
  o.x = f2bf(f.x); o.y = f2bf(f.y); o.z = f2bf(f.z); o.w = f2bf(f.w);
  reinterpret_cast<ushort4*>(out)[i] = o;
}

#define GLDS(srcp, dstp)                                                            \
  __builtin_amdgcn_global_load_lds(                                                 \
      (const __attribute__((address_space(1))) void*)(srcp),                        \
      (__attribute__((address_space(3))) void*)(dstp), 16, 0, 0)

// ---- NT GEMM: C[m][n] = sum_k A[m][k]*Bm[n][k] + bias[n]; A:MxK, Bm:NxK (row-major bf16) ----
// R7 = R6 structure (128x128 tile, 256 thr / 4 waves, BK=64, 32 KiB LDS, 3 blocks/CU,
// measured: occ 39%, VGPR 64, 0 conflicts) + scan1 FUSED into the MODE-1 epilogue.
//
// MODE 1 (GEMM1): block owns 64 channels (hidden rows [n0,n0+64) + gate [1024+n0,...)) and
// L-rows [bm,bm+128) = exactly 4 L-chunks of 32. Epilogue computes (lc,v) in fp32, stores
// them bf16 to hgb (as before), AND composes per-chunk summaries with the associative op
//   (A1,B1)∘(A2,B2) = (A1+A2, logaddexp(B1+A2, B2)),  element = (lc, v):
// thread composes its 4 consecutive rows per (mi,quad) segment; ordered cross-quad __shfl
// combine then mi-pair combine gives the 32-row chunk summary; quad==0 lanes write Ac/Bc.
// This deletes the scan_phase1 kernel (was a full 134 MB re-read).
// MODE 0: plain fp32 out + bias (GEMM2).
// XCD-aware block swizzle (grids 4096 / 1024, both %8==0). setprio(1) around MFMA.
template <int MODE>
__global__ __launch_bounds__(256, 3)
void gemm_bt(const ushort* __restrict__ A, const ushort* __restrict__ Bm,
             const float* __restrict__ bias, void* __restrict__ Cv,
             float* __restrict__ Acp, float* __restrict__ Bcp,
             int M, int N, int K) {
  __shared__ ushort As[128 * 64];
  __shared__ ushort Bs[128 * 64];
  const int tid  = threadIdx.x;
  const int wave = tid >> 6;
  const int lane = tid & 63;
  const int l15  = lane & 15;
  const int quad = lane >> 4;

  // XCD swizzle: dispatch index d goes to XCD d%8; give each XCD a contiguous logical chunk.
  int id = blockIdx.y * gridDim.x + blockIdx.x;
  const int nwg = gridDim.x * gridDim.y;
  id = (id & 7) * (nwg >> 3) + (id >> 3);
  const int bxi = id % gridDim.x;
  const int byi = id / gridDim.x;

  const long bm = (long)byi * 128;
  const int  wm = (wave >> 1) * 64;

  f32x4 acc[4][4];
#pragma unroll
  for (int i = 0; i < 4; ++i)
#pragma unroll
    for (int j = 0; j < 4; ++j) acc[i][j] = (f32x4){0.f, 0.f, 0.f, 0.f};

  // staging: wave fills rows [wave*32, wave*32+32); each instr covers 8 rows (64 lanes x 16B).
  const int rl  = lane >> 3;
  const int cb  = (lane & 7) ^ rl;
  const ushort* gA0 = A + (bm + wave * 32 + rl) * (long)K + cb * 8;
  long bRowBase;
  if (MODE == 1) {
    const long n0 = (long)bxi * 64;
    bRowBase = (wave < 2) ? (n0 + wave * 32) : (1024 + n0 + (wave - 2) * 32);
  } else {
    bRowBase = (long)bxi * 128 + wave * 32;
  }
  const ushort* gB0 = Bm + (bRowBase + rl) * (long)K + cb * 8;
  ushort* lA[4]; ushort* lB[4];
#pragma unroll
  for (int i = 0; i < 4; ++i) {
    lA[i] = &As[(wave * 32 + 8 * i) * 64];
    lB[i] = &Bs[(wave * 32 + 8 * i) * 64];
  }

  // fragment-read swizzled slot offsets: (kh*4+quad) ^ (l15&7)
  const int sq0 = ((0 * 4 + quad) ^ (l15 & 7)) * 8;
  const int sq1 = ((1 * 4 + quad) ^ (l15 & 7)) * 8;
  int arow[4], brow[4];
#pragma unroll
  for (int i = 0; i < 4; ++i) arow[i] = (wm + i * 16 + l15) * 64;
  if (MODE == 1) {
    const int wn0 = (wave & 1) * 32;   // 32 channels per wave; j<2 hidden, j>=2 gate
#pragma unroll
    for (int j = 0; j < 4; ++j) {
      const int trow = (j < 2) ? (wn0 + j * 16) : (64 + wn0 + (j - 2) * 16);
      brow[j] = (trow + l15) * 64;
    }
  } else {
    const int wn = (wave & 1) * 64;
#pragma unroll
    for (int j = 0; j < 4; ++j) brow[j] = (wn + j * 16 + l15) * 64;
  }

  for (int k0 = 0; k0 < K; k0 += 64) {
#pragma unroll
    for (int i = 0; i < 4; ++i)
      GLDS(gA0 + 8L * i * K + k0, lA[i]);
#pragma unroll
    for (int i = 0; i < 4; ++i)
      GLDS(gB0 + 8L * i * K + k0, lB[i]);
    __syncthreads();   // drains vmcnt -> LDS tile ready

#pragma unroll
    for (int kh = 0; kh < 2; ++kh) {
      const int sq = kh ? sq1 : sq0;
      s16x8 af[4], bf[4];
#pragma unroll
      for (int mi = 0; mi < 4; ++mi)
        af[mi] = *reinterpret_cast<const s16x8*>(&As[arow[mi] + sq]);
#pragma unroll
      for (int ni = 0; ni < 4; ++ni)
        bf[ni] = *reinterpret_cast<const s16x8*>(&Bs[brow[ni] + sq]);
      __builtin_amdgcn_s_setprio(1);
#pragma unroll
      for (int mi = 0; mi < 4; ++mi)
#pragma unroll
        for (int ni = 0; ni < 4; ++ni)
          acc[mi][ni] = mfma_bf16_16x16x32(af[mi], bf[ni], acc[mi][ni]);
      __builtin_amdgcn_s_setprio(0);
    }
    __syncthreads();   // protect LDS before next stage
  }

  // epilogue: C/D layout col = lane&15, row = quad*4 + reg
  if (MODE == 1) {
    const long n0  = (long)bxi * 64;
    const int  wn0 = (wave & 1) * 32;
    // per (mi, j): transform + store (lc,v), compose 4-row segment (rows quad*4+r)
    float sa[4][2], sb[4][2];
#pragma unroll
    for (int mi = 0; mi < 4; ++mi) {
      const long mrow = bm + wm + mi * 16 + quad * 4;
#pragma unroll
      for (int j = 0; j < 2; ++j) {
        const long ch = n0 + wn0 + j * 16 + l15;
        const float bh = bias[ch];
        const float bg = bias[1024 + ch];
        ushort* lp = (ushort*)Cv + mrow * (long)N + ch;
        float a = 0.f, bb = -INFINITY;
#pragma unroll
        for (int r = 0; r < 4; ++r) {
          float hd = acc[mi][j][r] + bh;
          float g  = acc[mi][j + 2][r] + bg;
          float lc, v; transform_f(hd, g, lc, v);
          lp[(long)r * N] = f2bf(lc);
          lp[(long)r * N + 1024] = f2bf(v);
          a += lc;
          bb = logaddexp_f(bb + lc, v);   // ordered: r ascending = L ascending
        }
        sa[mi][j] = a; sb[mi][j] = bb;
      }
    }
    // chunk summaries: wave-half covers 2 chunks (cc=0: mi 0,1; cc=1: mi 2,3).
    // L-order within chunk: (mi_lo, q0..q3), (mi_hi, q0..q3); segs gathered cross-quad.
#pragma unroll
    for (int j = 0; j < 2; ++j) {
#pragma unroll
      for (int cc = 0; cc < 2; ++cc) {
        float A = 0.f, Bb = -INFINITY;
#pragma unroll
        for (int mi = 2 * cc; mi < 2 * cc + 2; ++mi) {
#pragma unroll
          for (int q = 0; q < 4; ++q) {
            float qa = __shfl(sa[mi][j], l15 + 16 * q);
            float qb = __shfl(sb[mi][j], l15 + 16 * q);
            Bb = logaddexp_f(Bb + qa, qb);
            A += qa;
          }
        }
        if (quad == 0) {
          const long gc = (bm + wm + cc * 32) >> 5;   // == b*NC_ + c  (L_/32 == NC_)
          const long ch = n0 + wn0 + j * 16 + l15;
          Acp[gc * H_ + ch] = A;
          Bcp[gc * H_ + ch] = Bb;
        }
      }
    }
  } else {
    const int wn = (wave & 1) * 64;
#pragma unroll
    for (int mi = 0; mi < 4; ++mi) {
      const long mrow = bm + wm + mi * 16 + quad * 4;
#pragma unroll
      for (int ni = 0; ni < 4; ++ni) {
        const long ncol = (long)bxi * 128 + wn + ni * 16 + l15;
        const float bv = bias[ncol];
        float* cp = (float*)Cv + mrow * (long)N + ncol;
#pragma unroll
        for (int r = 0; r < 4; ++r) cp[(long)r * N] = acc[mi][ni][r] + bv;
      }
    }
  }
}

// phase 2 (wave-parallel): carry[c] = B-component of the exclusive ∘-scan of chunk pairs.
// One wave per (b,h): lane i composes chunks 4i..4i+3, 6-step shfl_up inclusive scan,
// shift to exclusive, then each lane emits its 4 carries. 1024 blocks (full chip).
__global__ void scan_phase2(const float* __restrict__ Ac, const float* __restrict__ Bc,
                            float* __restrict__ carry) {
  const int wid  = (blockIdx.x * blockDim.x + threadIdx.x) >> 6;  // 0 .. B_*H_-1
  const int lane = threadIdx.x & 63;
  const int h = wid & (H_ - 1);
  const int b = wid >> 10;
  const size_t base = (size_t)b * NC_ * H_ + h;
  float pa[4], pb[4];
#pragma unroll
  for (int k = 0; k < 4; ++k) {
    size_t o = base + (size_t)(4 * lane + k) * H_;
    pa[k] = Ac[o]; pb[k] = Bc[o];
  }
  // local compose (ordered)
  float sA = pa[0], sB = pb[0];
#pragma unroll
  for (int k = 1; k < 4; ++k) { sB = logaddexp_f(sB + pa[k], pb[k]); sA += pa[k]; }
  // inclusive wave scan under ∘ (prev from lower lane is LEFT operand)
  float iA = sA, iB = sB;
#pragma unroll
  for (int d = 1; d < 64; d <<= 1) {
    float uA = __shfl_up(iA, d);
    float uB = __shfl_up(iB, d);
    if (lane >= d) { iB = logaddexp_f(uB + iA, iB); iA = uA + iA; }
  }
  // exclusive
  float eA = __shfl_up(iA, 1);
  float eB = __shfl_up(iB, 1);
  if (lane == 0) { eA = 0.f; eB = -INFINITY; }
  // emit carries for this lane's 4 chunks
  float Bst = eB, Ast = eA;
#pragma unroll
  for (int k = 0; k < 4; ++k) {
    size_t o = base + (size_t)(4 * lane + k) * H_;
    carry[o] = Bst;
    Bst = logaddexp_f(Bst + pa[k], pb[k]);
    Ast += pa[k];
  }
}

// phase 3: re-scan chunk with carry, emit h = exp(log_h) as bf16 (4 channels/thread)
__global__ void scan_phase3(const ushort* __restrict__ hg, const float* __restrict__ carry,
                            ushort* __restrict__ hb) {
  int gid = blockIdx.x * blockDim.x + threadIdx.x;  // B_*NC_*H_/4
  int hq = gid & (H_ / 4 - 1);
  int c  = (gid >> 8) & (NC_ - 1);
  int b  = gid >> 16;
  float4 cr = *reinterpret_cast<const float4*>(&carry[(size_t)(b * NC_ + c) * H_ + hq * 4]);
  float lh[4] = {cr.x, cr.y, cr.z, cr.w};
  const ushort* p = hg + ((size_t)(b * L_ + c * LC_) * (2 * H_)) + hq * 4;
  ushort* q = hb + (size_t)(b * L_ + c * LC_) * H_ + hq * 4;
#pragma unroll 4
  for (int l = 0; l < LC_; ++l) {
    ushort4 lc4 = *reinterpret_cast<const ushort4*>(p);
    ushort4 v4  = *reinterpret_cast<const ushort4*>(p + H_);
    float lcv[4] = {bf2f(lc4.x), bf2f(lc4.y), bf2f(lc4.z), bf2f(lc4.w)};
    float vv[4]  = {bf2f(v4.x),  bf2f(v4.y),  bf2f(v4.z),  bf2f(v4.w)};
    ushort4 o;
    ushort* op = &o.x;
#pragma unroll
    for (int j = 0; j < 4; ++j) {
      lh[j] = logaddexp_f(lh[j] + lcv[j], vv[j]);
      op[j] = f2bf(__expf(lh[j]));
    }
    *reinterpret_cast<ushort4*>(q) = o;
    p += 2 * H_;
    q += H_;
  }
}

extern "C" void kernel_launch(void* const* d_in, const int* in_sizes, int n_in,
                              void* d_out, int out_size, void* d_ws, size_t ws_size,
                              hipStream_t stream) {
  const float* x     = (const float*)d_in[0];
  const float* W_in  = (const float*)d_in[1];
  const float* b_in  = (const float*)d_in[2];
  const float* W_out = (const float*)d_in[3];
  const float* b_out = (const float*)d_in[4];
  float* out = (float*)d_out;

  char* ws = (char*)d_ws;
  size_t off = 0;
  auto alloc = [&](size_t bytes) {
    void* p = ws + off;
    off = (off + bytes + 255) & ~(size_t)255;
    return p;
  };
  // region shared by xb (alive: cast -> GEMM1) and hb (alive: phase3 -> GEMM2)
  ushort* xb    = (ushort*)alloc((size_t)B_ * L_ * H_ * 2);       // 67 MB (union)
  ushort* hb    = xb;
  ushort* Wib   = (ushort*)alloc((size_t)2 * H_ * D_ * 2);        // 2 MB
  ushort* Wob   = (ushort*)alloc((size_t)D_ * H_ * 2);            // 1 MB
  ushort* hgb   = (ushort*)alloc((size_t)B_ * L_ * 2 * H_ * 2);   // 134 MB (bf16: lc, v)
  float*  Ac    = (float*)alloc((size_t)B_ * NC_ * H_ * 4);       // 4 MB
  float*  Bc    = (float*)alloc((size_t)B_ * NC_ * H_ * 4);       // 4 MB
  float*  carry = (float*)alloc((size_t)B_ * NC_ * H_ * 4);       // 4 MB
  // total ~216 MB

  // casts to bf16
  cast_kernel<<<(B_ * L_ * D_ / 4 + 255) / 256, 256, 0, stream>>>(x, xb, B_ * L_ * D_ / 4);
  {
    int n0 = 2 * H_ * D_ / 4, n1 = D_ * H_ / 4;
    cast2_kernel<<<(n0 + n1 + 255) / 256, 256, 0, stream>>>(W_in, Wib, n0, W_out, Wob, n1);
  }

  // GEMM1: (lc, v) = transform(x . W_in^T + b_in)  AND chunk summaries (Ac, Bc)
  // grid.x = 1024 channels / 64 per block = 16; grid = 4096 blocks.
  gemm_bt<1><<<dim3(16, (B_ * L_) / 128), 256, 0, stream>>>(
      xb, Wib, b_in, hgb, Ac, Bc, B_ * L_, 2 * H_, D_);

  // exclusive scan over chunk summaries -> carries (one wave per (b,h))
  scan_phase2<<<(B_ * H_ * 64) / 256, 256, 0, stream>>>(Ac, Bc, carry);
  // re-scan chunks with carry, emit h (bf16)
  scan_phase3<<<(B_ * NC_ * H_ / 4) / 256, 256, 0, stream>>>(hgb, carry, hb);

  // GEMM2: out = h . W_out^T + b_out   (M=32768, N=512, K=1024), fp32 out
  // grid = 4 x 256 = 1024 blocks.
  gemm_bt<0><<<dim3(D_ / 128, (B_ * L_) / 128), 256, 0, stream>>>(
      hb, Wob, b_out, out, nullptr, nullptr, B_ * L_, D_, H_);
}

// Round 8
// 346.015 us; speedup vs baseline: 2.5172x; 1.0567x over previous
//
#include <hip/hip_runtime.h>
#include <hip/hip_bf16.h>
#include <cstdint>
#include <cstddef>

#define B_ 4
#define L_ 8192
#define D_ 512
#define H_ 1024
#define NC_ 256           // chunks along L for the 3-phase scan
#define LC_ (L_ / NC_)    // 32

typedef float  f32x4 __attribute__((ext_vector_type(4)));
typedef short  s16x8 __attribute__((ext_vector_type(8)));
typedef __bf16 b16x8 __attribute__((ext_vector_type(8)));

// ---- MFMA wrapper: tolerate either builtin signature (v8i16 or v8bf16) ----
template <typename T, typename U>
__device__ inline auto mfma_sel(T a, T b, f32x4 c, U, int)
    -> decltype(__builtin_amdgcn_mfma_f32_16x16x32_bf16(a, b, c, 0, 0, 0)) {
  return __builtin_amdgcn_mfma_f32_16x16x32_bf16(a, b, c, 0, 0, 0);
}
template <typename T, typename U>
__device__ inline f32x4 mfma_sel(T a, T b, f32x4 c, U, long) {
  return __builtin_amdgcn_mfma_f32_16x16x32_bf16(
      __builtin_bit_cast(U, a), __builtin_bit_cast(U, b), c, 0, 0, 0);
}
__device__ inline f32x4 mfma_bf16_16x16x32(s16x8 a, s16x8 b, f32x4 c) {
  return mfma_sel(a, b, c, b16x8{}, 0);
}

// ---- fp32 <-> bf16 ----
__device__ inline ushort f2bf(float f) {
  uint32_t u = __builtin_bit_cast(uint32_t, f);
  uint32_t r = (u + 0x7fffu + ((u >> 16) & 1u)) >> 16;
  return (ushort)r;
}
__device__ inline float bf2f(ushort u) {
  return __builtin_bit_cast(float, (uint32_t)u << 16);
}

// ---- scan math helpers ----
__device__ inline float softplus_f(float x) {
  return fmaxf(x, 0.f) + __logf(1.f + __expf(-fabsf(x)));
}
__device__ inline float logaddexp_f(float a, float b) {
  float m = fmaxf(a, b);
  return m + __logf(1.f + __expf(-fabsf(a - b)));
}
// from (hidden, gate): lc = -softplus(g); v = log_z + log_tilde_h
__device__ inline void transform_f(float hd, float g, float& lc, float& v) {
  float sp = softplus_f(g);
  lc = -sp;
  float lz = g - sp;                       // -softplus(-g)
  float lth = (hd >= 0.f) ? __logf(hd + 0.5f) : (hd - softplus_f(hd));
  v = lz + lth;
}

__global__ void cast_kernel(const float* __restrict__ in, ushort* __restrict__ out, int n4) {
  int i = blockIdx.x * blockDim.x + threadIdx.x;
  if (i >= n4) return;
  float4 f = reinterpret_cast<const float4*>(in)[i];
  ushort4 o;
  o.x = f2bf(f.x); o.y = f2bf(f.y); o.z = f2bf(f.z); o.w = f2bf(f.w);
  reinterpret_cast<ushort4*>(out)[i] = o;
}

// both weights in one launch
__global__ void cast2_kernel(const float* __restrict__ in0, ushort* __restrict__ out0, int n4_0,
                             const float* __restrict__ in1, ushort* __restrict__ out1, int n4_1) {
  int i = blockIdx.x * blockDim.x + threadIdx.x;
  const float* in; ushort* out;
  if (i < n4_0) { in = in0; out = out0; }
  else { i -= n4_0; if (i >= n4_1) return; in = in1; out = out1; }
  float4 f = reinterpret_cast<const float4*>(in)[i];
  ushort4 o;
  o.x = f2bf(f.x); o.y = f2bf(f.y); o.z = f2bf(f.z); o.w = f2bf(f.w);
  reinterpret_cast<ushort4*>(out)[i] = o;
}

#define GLDS(srcp, dstp)                                                            \
  __builtin_amdgcn_global_load_lds(                                                 \
      (const __attribute__((address_space(1))) void*)(srcp),                        \
      (__attribute__((address_space(3))) void*)(dstp), 16, 0, 0)

// ---- NT GEMM: C[m][n] = sum_k A[m][k]*Bm[n][k] + bias[n]; A:MxK, Bm:NxK (row-major bf16) ----
// R8 = R7 structure with two VALU cuts (G1 was 83% VALUBusy):
//  (a) K templated (KC) + full K-loop unroll: constant k0 folds into global_load_lds
//      offset fields (m254) -> deletes ~32 VALU/K-step of 64-bit address increments.
//  (b) MODE-1 fused scan1 compose rewritten in scaled-sum form: per 4-row segment keep
//      (seg_lc_sum, max_t, sum_exp) computed with ADDS + 4 exp (no logaddexp chain);
//      chunk combine = 2-step shuffle suffix-scan of lc-sums + max/sum xor-reduces.
//      Transcendentals/thread: ~64exp+64log -> 40exp+4log; serial chains -> trees.
// Geometry unchanged (proven R6): 128x128 tile, 256 thr/4 waves, BK=64, 32 KiB LDS,
// launch_bounds(256,3) -> 3 blocks/CU, VGPR<170 (watch WRITE_SIZE for spill).
// LDS swizzle: phys chunk p of row r holds logical chunk p^(r&7); staging lane
// (rl=lane>>3, slot=lane&7) fetches global chunk slot^rl; frag read (kh*4+quad)^(l15&7).
// 0 bank conflicts measured R0-R7. XCD-aware block swizzle. setprio(1) around MFMA.
template <int MODE, int KC>
__global__ __launch_bounds__(256, 3)
void gemm_bt(const ushort* __restrict__ A, const ushort* __restrict__ Bm,
             const float* __restrict__ bias, void* __restrict__ Cv,
             float* __restrict__ Acp, float* __restrict__ Bcp,
             int M, int N) {
  __shared__ ushort As[128 * 64];
  __shared__ ushort Bs[128 * 64];
  const int tid  = threadIdx.x;
  const int wave = tid >> 6;
  const int lane = tid & 63;
  const int l15  = lane & 15;
  const int quad = lane >> 4;

  // XCD swizzle: dispatch index d goes to XCD d%8; give each XCD a contiguous logical chunk.
  int id = blockIdx.y * gridDim.x + blockIdx.x;
  const int nwg = gridDim.x * gridDim.y;
  id = (id & 7) * (nwg >> 3) + (id >> 3);
  const int bxi = id % gridDim.x;
  const int byi = id / gridDim.x;

  const long bm = (long)byi * 128;
  const int  wm = (wave >> 1) * 64;

  f32x4 acc[4][4];
#pragma unroll
  for (int i = 0; i < 4; ++i)
#pragma unroll
    for (int j = 0; j < 4; ++j) acc[i][j] = (f32x4){0.f, 0.f, 0.f, 0.f};

  // staging: wave fills rows [wave*32, wave*32+32); each instr covers 8 rows (64 lanes x 16B).
  const int rl  = lane >> 3;
  const int cb  = (lane & 7) ^ rl;
  const ushort* gA0 = A + (bm + wave * 32 + rl) * (long)KC + cb * 8;
  long bRowBase;
  if (MODE == 1) {
    const long n0 = (long)bxi * 64;
    bRowBase = (wave < 2) ? (n0 + wave * 32) : (1024 + n0 + (wave - 2) * 32);
  } else {
    bRowBase = (long)bxi * 128 + wave * 32;
  }
  const ushort* gB0 = Bm + (bRowBase + rl) * (long)KC + cb * 8;
  ushort* lA[4]; ushort* lB[4];
#pragma unroll
  for (int i = 0; i < 4; ++i) {
    lA[i] = &As[(wave * 32 + 8 * i) * 64];
    lB[i] = &Bs[(wave * 32 + 8 * i) * 64];
  }

  // fragment-read swizzled slot offsets: (kh*4+quad) ^ (l15&7)
  const int sq0 = ((0 * 4 + quad) ^ (l15 & 7)) * 8;
  const int sq1 = ((1 * 4 + quad) ^ (l15 & 7)) * 8;
  int arow[4], brow[4];
#pragma unroll
  for (int i = 0; i < 4; ++i) arow[i] = (wm + i * 16 + l15) * 64;
  if (MODE == 1) {
    const int wn0 = (wave & 1) * 32;   // 32 channels per wave; j<2 hidden, j>=2 gate
#pragma unroll
    for (int j = 0; j < 4; ++j) {
      const int trow = (j < 2) ? (wn0 + j * 16) : (64 + wn0 + (j - 2) * 16);
      brow[j] = (trow + l15) * 64;
    }
  } else {
    const int wn = (wave & 1) * 64;
#pragma unroll
    for (int j = 0; j < 4; ++j) brow[j] = (wn + j * 16 + l15) * 64;
  }

  // fully-unrolled K loop: k0 is a compile-time constant each iteration -> the
  // +k0 on the global pointers folds into the load-instruction offset field.
#pragma unroll
  for (int k0 = 0; k0 < KC; k0 += 64) {
#pragma unroll
    for (int i = 0; i < 4; ++i)
      GLDS(gA0 + 8L * i * KC + k0, lA[i]);
#pragma unroll
    for (int i = 0; i < 4; ++i)
      GLDS(gB0 + 8L * i * KC + k0, lB[i]);
    __syncthreads();   // drains vmcnt -> LDS tile ready

#pragma unroll
    for (int kh = 0; kh < 2; ++kh) {
      const int sq = kh ? sq1 : sq0;
      s16x8 af[4], bf[4];
#pragma unroll
      for (int mi = 0; mi < 4; ++mi)
        af[mi] = *reinterpret_cast<const s16x8*>(&As[arow[mi] + sq]);
#pragma unroll
      for (int ni = 0; ni < 4; ++ni)
        bf[ni] = *reinterpret_cast<const s16x8*>(&Bs[brow[ni] + sq]);
      __builtin_amdgcn_s_setprio(1);
#pragma unroll
      for (int mi = 0; mi < 4; ++mi)
#pragma unroll
        for (int ni = 0; ni < 4; ++ni)
          acc[mi][ni] = mfma_bf16_16x16x32(af[mi], bf[ni], acc[mi][ni]);
      __builtin_amdgcn_s_setprio(0);
    }
    __syncthreads();   // protect LDS before next stage
  }

  // epilogue: C/D layout col = lane&15, row = quad*4 + reg
  if (MODE == 1) {
    const long n0  = (long)bxi * 64;
    const int  wn0 = (wave & 1) * 32;
    // Per 4-row segment (mi, j): transform + store (lc,v); build scaled-sum summary
    //   ea = sum lc; em = max_r t_r; es = sum_r exp(t_r - em),  t_r = v_r + suffix_lc.
    float ea[4][2], em[4][2], es[4][2];
#pragma unroll
    for (int mi = 0; mi < 4; ++mi) {
      const long mrow = bm + wm + mi * 16 + quad * 4;
#pragma unroll
      for (int j = 0; j < 2; ++j) {
        const long ch = n0 + wn0 + j * 16 + l15;
        const float bh = bias[ch];
        const float bg = bias[1024 + ch];
        ushort* lp = (ushort*)Cv + mrow * (long)N + ch;
        float lcr[4], vr[4];
#pragma unroll
        for (int r = 0; r < 4; ++r) {
          float hd = acc[mi][j][r] + bh;
          float g  = acc[mi][j + 2][r] + bg;
          transform_f(hd, g, lcr[r], vr[r]);
          lp[(long)r * N] = f2bf(lcr[r]);
          lp[(long)r * N + 1024] = f2bf(vr[r]);
        }
        float run = 0.f, ms = -INFINITY;
        float t0, t1, t2, t3;
        t3 = vr[3];            ms = t3;             run += lcr[3];
        t2 = vr[2] + run;      ms = fmaxf(ms, t2);  run += lcr[2];
        t1 = vr[1] + run;      ms = fmaxf(ms, t1);  run += lcr[1];
        t0 = vr[0] + run;      ms = fmaxf(ms, t0);  run += lcr[0];
        float ss = __expf(t0 - ms) + __expf(t1 - ms) + __expf(t2 - ms) + __expf(t3 - ms);
        ea[mi][j] = run; em[mi][j] = ms; es[mi][j] = ss;
      }
    }
    // chunk combine per (j, cc): chunk = segments (mloc 0,1) x (quad 0..3), L-order
    // p = mloc*16 + quad*4 + r. Suffix lc-sums across quads via 2-step shfl_down scan.
#pragma unroll
    for (int j = 0; j < 2; ++j) {
#pragma unroll
      for (int cc = 0; cc < 2; ++cc) {
        const int mi0 = 2 * cc, mi1 = 2 * cc + 1;
        float suf0 = ea[mi0][j], suf1 = ea[mi1][j];
        { float tt = __shfl_down(suf0, 16); if (quad < 3) suf0 += tt;
          tt = __shfl_down(suf0, 32); if (quad < 2) suf0 += tt; }
        { float tt = __shfl_down(suf1, 16); if (quad < 3) suf1 += tt;
          tt = __shfl_down(suf1, 32); if (quad < 2) suf1 += tt; }
        const float tot0 = __shfl(suf0, l15);   // total lc, mloc 0 (quad0 holds full sum)
        const float tot1 = __shfl(suf1, l15);   // total lc, mloc 1
        // u = segment max + lc-sum of all LATER segments in the chunk
        float u0 = em[mi0][j] + (suf0 - ea[mi0][j]) + tot1;
        float u1 = em[mi1][j] + (suf1 - ea[mi1][j]);
        float Mx = fmaxf(u0, u1);
        Mx = fmaxf(Mx, __shfl_xor(Mx, 16));
        Mx = fmaxf(Mx, __shfl_xor(Mx, 32));
        float contrib = __expf(u0 - Mx) * es[mi0][j] + __expf(u1 - Mx) * es[mi1][j];
        contrib += __shfl_xor(contrib, 16);
        contrib += __shfl_xor(contrib, 32);
        if (quad == 0) {
          const long gc = (bm + wm + cc * 32) >> 5;   // == b*NC_ + c  (L_/32 == NC_)
          const long ch = n0 + wn0 + j * 16 + l15;
          Acp[gc * H_ + ch] = tot0 + tot1;
          Bcp[gc * H_ + ch] = Mx + __logf(contrib);
        }
      }
    }
  } else {
    const int wn = (wave & 1) * 64;
#pragma unroll
    for (int mi = 0; mi < 4; ++mi) {
      const long mrow = bm + wm + mi * 16 + quad * 4;
#pragma unroll
      for (int ni = 0; ni < 4; ++ni) {
        const long ncol = (long)bxi * 128 + wn + ni * 16 + l15;
        const float bv = bias[ncol];
        float* cp = (float*)Cv + mrow * (long)N + ncol;
#pragma unroll
        for (int r = 0; r < 4; ++r) cp[(long)r * N] = acc[mi][ni][r] + bv;
      }
    }
  }
}

// phase 2 (wave-parallel): carry[c] = B-component of the exclusive ∘-scan of chunk pairs.
// One wave per (b,h): lane i composes chunks 4i..4i+3, 6-step shfl_up inclusive scan,
// shift to exclusive, then each lane emits its 4 carries. 1024 blocks (full chip).
__global__ void scan_phase2(const float* __restrict__ Ac, const float* __restrict__ Bc,
                            float* __restrict__ carry) {
  const int wid  = (blockIdx.x * blockDim.x + threadIdx.x) >> 6;  // 0 .. B_*H_-1
  const int lane = threadIdx.x & 63;
  const int h = wid & (H_ - 1);
  const int b = wid >> 10;
  const size_t base = (size_t)b * NC_ * H_ + h;
  float pa[4], pb[4];
#pragma unroll
  for (int k = 0; k < 4; ++k) {
    size_t o = base + (size_t)(4 * lane + k) * H_;
    pa[k] = Ac[o]; pb[k] = Bc[o];
  }
  // local compose (ordered)
  float sA = pa[0], sB = pb[0];
#pragma unroll
  for (int k = 1; k < 4; ++k) { sB = logaddexp_f(sB + pa[k], pb[k]); sA += pa[k]; }
  // inclusive wave scan under ∘ (prev from lower lane is LEFT operand)
  float iA = sA, iB = sB;
#pragma unroll
  for (int d = 1; d < 64; d <<= 1) {
    float uA = __shfl_up(iA, d);
    float uB = __shfl_up(iB, d);
    if (lane >= d) { iB = logaddexp_f(uB + iA, iB); iA = uA + iA; }
  }
  // exclusive
  float eA = __shfl_up(iA, 1);
  float eB = __shfl_up(iB, 1);
  if (lane == 0) { eA = 0.f; eB = -INFINITY; }
  // emit carries for this lane's 4 chunks
  float Bst = eB;
#pragma unroll
  for (int k = 0; k < 4; ++k) {
    size_t o = base + (size_t)(4 * lane + k) * H_;
    carry[o] = Bst;
    Bst = logaddexp_f(Bst + pa[k], pb[k]);
  }
}

// phase 3: re-scan chunk with carry, emit h = exp(log_h) as bf16 (4 channels/thread)
__global__ void scan_phase3(const ushort* __restrict__ hg, const float* __restrict__ carry,
                            ushort* __restrict__ hb) {
  int gid = blockIdx.x * blockDim.x + threadIdx.x;  // B_*NC_*H_/4
  int hq = gid & (H_ / 4 - 1);
  int c  = (gid >> 8) & (NC_ - 1);
  int b  = gid >> 16;
  float4 cr = *reinterpret_cast<const float4*>(&carry[(size_t)(b * NC_ + c) * H_ + hq * 4]);
  float lh[4] = {cr.x, cr.y, cr.z, cr.w};
  const ushort* p = hg + ((size_t)(b * L_ + c * LC_) * (2 * H_)) + hq * 4;
  ushort* q = hb + (size_t)(b * L_ + c * LC_) * H_ + hq * 4;
#pragma unroll 4
  for (int l = 0; l < LC_; ++l) {
    ushort4 lc4 = *reinterpret_cast<const ushort4*>(p);
    ushort4 v4  = *reinterpret_cast<const ushort4*>(p + H_);
    float lcv[4] = {bf2f(lc4.x), bf2f(lc4.y), bf2f(lc4.z), bf2f(lc4.w)};
    float vv[4]  = {bf2f(v4.x),  bf2f(v4.y),  bf2f(v4.z),  bf2f(v4.w)};
    ushort4 o;
    ushort* op = &o.x;
#pragma unroll
    for (int j = 0; j < 4; ++j) {
      lh[j] = logaddexp_f(lh[j] + lcv[j], vv[j]);
      op[j] = f2bf(__expf(lh[j]));
    }
    *reinterpret_cast<ushort4*>(q) = o;
    p += 2 * H_;
    q += H_;
  }
}

extern "C" void kernel_launch(void* const* d_in, const int* in_sizes, int n_in,
                              void* d_out, int out_size, void* d_ws, size_t ws_size,
                              hipStream_t stream) {
  const float* x     = (const float*)d_in[0];
  const float* W_in  = (const float*)d_in[1];
  const float* b_in  = (const float*)d_in[2];
  const float* W_out = (const float*)d_in[3];
  const float* b_out = (const float*)d_in[4];
  float* out = (float*)d_out;

  char* ws = (char*)d_ws;
  size_t off = 0;
  auto alloc = [&](size_t bytes) {
    void* p = ws + off;
    off = (off + bytes + 255) & ~(size_t)255;
    return p;
  };
  // region shared by xb (alive: cast -> GEMM1) and hb (alive: phase3 -> GEMM2)
  ushort* xb    = (ushort*)alloc((size_t)B_ * L_ * H_ * 2);       // 67 MB (union)
  ushort* hb    = xb;
  ushort* Wib   = (ushort*)alloc((size_t)2 * H_ * D_ * 2);        // 2 MB
  ushort* Wob   = (ushort*)alloc((size_t)D_ * H_ * 2);            // 1 MB
  ushort* hgb   = (ushort*)alloc((size_t)B_ * L_ * 2 * H_ * 2);   // 134 MB (bf16: lc, v)
  float*  Ac    = (float*)alloc((size_t)B_ * NC_ * H_ * 4);       // 4 MB
  float*  Bc    = (float*)alloc((size_t)B_ * NC_ * H_ * 4);       // 4 MB
  float*  carry = (float*)alloc((size_t)B_ * NC_ * H_ * 4);       // 4 MB
  // total ~216 MB

  // casts to bf16
  cast_kernel<<<(B_ * L_ * D_ / 4 + 255) / 256, 256, 0, stream>>>(x, xb, B_ * L_ * D_ / 4);
  {
    int n0 = 2 * H_ * D_ / 4, n1 = D_ * H_ / 4;
    cast2_kernel<<<(n0 + n1 + 255) / 256, 256, 0, stream>>>(W_in, Wib, n0, W_out, Wob, n1);
  }

  // GEMM1: (lc, v) = transform(x . W_in^T + b_in)  AND chunk summaries (Ac, Bc)
  // grid.x = 1024 channels / 64 per block = 16; grid = 4096 blocks. K = 512 (templated).
  gemm_bt<1, 512><<<dim3(16, (B_ * L_) / 128), 256, 0, stream>>>(
      xb, Wib, b_in, hgb, Ac, Bc, B_ * L_, 2 * H_);

  // exclusive scan over chunk summaries -> carries (one wave per (b,h))
  scan_phase2<<<(B_ * H_ * 64) / 256, 256, 0, stream>>>(Ac, Bc, carry);
  // re-scan chunks with carry, emit h (bf16)
  scan_phase3<<<(B_ * NC_ * H_ / 4) / 256, 256, 0, stream>>>(hgb, carry, hb);

  // GEMM2: out = h . W_out^T + b_out   (M=32768, N=512, K=1024 templated), fp32 out
  // grid = 4 x 256 = 1024 blocks.
  gemm_bt<0, 1024><<<dim3(D_ / 128, (B_ * L_) / 128), 256, 0, stream>>>(
      hb, Wob, b_out, out, nullptr, nullptr, B_ * L_, D_);
}

// Round 9
// 345.226 us; speedup vs baseline: 2.5229x; 1.0023x over previous
//
#include <hip/hip_runtime.h>
#include <hip/hip_bf16.h>
#include <cstdint>
#include <cstddef>

#define B_ 4
#define L_ 8192
#define D_ 512
#define H_ 1024
#define NC_ 256           // chunks along L for the 3-phase scan
#define LC_ (L_ / NC_)    // 32

typedef float  f32x4 __attribute__((ext_vector_type(4)));
typedef short  s16x8 __attribute__((ext_vector_type(8)));
typedef __bf16 b16x8 __attribute__((ext_vector_type(8)));

// ---- MFMA wrapper: tolerate either builtin signature (v8i16 or v8bf16) ----
template <typename T, typename U>
__device__ inline auto mfma_sel(T a, T b, f32x4 c, U, int)
    -> decltype(__builtin_amdgcn_mfma_f32_16x16x32_bf16(a, b, c, 0, 0, 0)) {
  return __builtin_amdgcn_mfma_f32_16x16x32_bf16(a, b, c, 0, 0, 0);
}
template <typename T, typename U>
__device__ inline f32x4 mfma_sel(T a, T b, f32x4 c, U, long) {
  return __builtin_amdgcn_mfma_f32_16x16x32_bf16(
      __builtin_bit_cast(U, a), __builtin_bit_cast(U, b), c, 0, 0, 0);
}
__device__ inline f32x4 mfma_bf16_16x16x32(s16x8 a, s16x8 b, f32x4 c) {
  return mfma_sel(a, b, c, b16x8{}, 0);
}

// ---- fp32 <-> bf16 ----
__device__ inline ushort f2bf(float f) {
  uint32_t u = __builtin_bit_cast(uint32_t, f);
  uint32_t r = (u + 0x7fffu + ((u >> 16) & 1u)) >> 16;
  return (ushort)r;
}
__device__ inline float bf2f(ushort u) {
  return __builtin_bit_cast(float, (uint32_t)u << 16);
}

// ---- scan math helpers ----
__device__ inline float softplus_f(float x) {
  return fmaxf(x, 0.f) + __logf(1.f + __expf(-fabsf(x)));
}
__device__ inline float logaddexp_f(float a, float b) {
  float m = fmaxf(a, b);
  return m + __logf(1.f + __expf(-fabsf(a - b)));
}
// from (hidden, gate): lc = -softplus(g); v = log_z + log_tilde_h
__device__ inline void transform_f(float hd, float g, float& lc, float& v) {
  float sp = softplus_f(g);
  lc = -sp;
  float lz = g - sp;                       // -softplus(-g)
  float lth = (hd >= 0.f) ? __logf(hd + 0.5f) : (hd - softplus_f(hd));
  v = lz + lth;
}

// one launch for all three bf16 casts (x, W_in, W_out)
__global__ void cast3_kernel(const float* __restrict__ in0, ushort* __restrict__ out0, int n0,
                             const float* __restrict__ in1, ushort* __restrict__ out1, int n1,
                             const float* __restrict__ in2, ushort* __restrict__ out2, int n2) {
  int i = blockIdx.x * blockDim.x + threadIdx.x;
  const float* in; ushort* out;
  if (i < n0) { in = in0; out = out0; }
  else {
    i -= n0;
    if (i < n1) { in = in1; out = out1; }
    else { i -= n1; if (i >= n2) return; in = in2; out = out2; }
  }
  float4 f = reinterpret_cast<const float4*>(in)[i];
  ushort4 o;
  o.x = f2bf(f.x); o.y = f2bf(f.y); o.z = f2bf(f.z); o.w = f2bf(f.w);
  reinterpret_cast<ushort4*>(out)[i] = o;
}

#define GLDS(srcp, dstp)                                                            \
  __builtin_amdgcn_global_load_lds(                                                 \
      (const __attribute__((address_space(1))) void*)(srcp),                        \
      (__attribute__((address_space(3))) void*)(dstp), 16, 0, 0)

// ---- NT GEMM: C[m][n] = sum_k A[m][k]*Bm[n][k] + bias[n]; A:MxK, Bm:NxK (row-major bf16) ----
// R9 = R8 K-loop/epilogue, made PERSISTENT: grid = 768 blocks (3/CU, measured residency),
// each block loops jobs (job += 768). After the final K-step's trailing barrier the block
// issues the NEXT job's stage-0 global_load_lds (LDS free: all reads done at that barrier;
// epilogue touches only regs/global), then runs the epilogue -> next job's first
// __syncthreads finds the tile landed. Removes the per-job cold-start stall (was 16/CU for
// GEMM1) and hides stage latency under epilogue VALU. Job swizzle unchanged and XCD-stable:
// 768%8==0 => job%8 == blockIdx%8 for every iteration of a block.
// Geometry (proven R6-R8): 128x128 tile, 256 thr/4 waves, BK=64, 32 KiB LDS,
// launch_bounds(256,3), VGPR ~70 (watch WRITE_SIZE for spill). LDS swizzle: phys chunk p of
// row r holds logical chunk p^(r&7); staging lane (rl=lane>>3, slot=lane&7) fetches global
// chunk slot^rl; frag read (kh*4+quad)^(l15&7). 0 bank conflicts R0-R8.
// MODE 1 (GEMM1): fused transform + scan1 chunk-compose epilogue (scaled-sum form, R8).
// MODE 0: plain fp32 out + bias.
template <int MODE, int KC>
__global__ __launch_bounds__(256, 3)
void gemm_bt(const ushort* __restrict__ A, const ushort* __restrict__ Bm,
             const float* __restrict__ bias, void* __restrict__ Cv,
             float* __restrict__ Acp, float* __restrict__ Bcp,
             int M, int N, int nbx, int njobs) {
  __shared__ ushort As[128 * 64];
  __shared__ ushort Bs[128 * 64];
  const int tid  = threadIdx.x;
  const int wave = tid >> 6;
  const int lane = tid & 63;
  const int l15  = lane & 15;
  const int quad = lane >> 4;
  const int nblk = gridDim.x;

  const int wm = (wave >> 1) * 64;

  // staging lane map: wave fills rows [wave*32, wave*32+32); each instr = 8 rows x 16B/lane.
  const int rl  = lane >> 3;
  const int cb  = (lane & 7) ^ rl;
  ushort* lA[4]; ushort* lB[4];
#pragma unroll
  for (int i = 0; i < 4; ++i) {
    lA[i] = &As[(wave * 32 + 8 * i) * 64];
    lB[i] = &Bs[(wave * 32 + 8 * i) * 64];
  }

  // fragment-read swizzled slot offsets: (kh*4+quad) ^ (l15&7)
  const int sq0 = ((0 * 4 + quad) ^ (l15 & 7)) * 8;
  const int sq1 = ((1 * 4 + quad) ^ (l15 & 7)) * 8;
  int arow[4], brow[4];
#pragma unroll
  for (int i = 0; i < 4; ++i) arow[i] = (wm + i * 16 + l15) * 64;
  if (MODE == 1) {
    const int wn0 = (wave & 1) * 32;   // 32 channels per wave; j<2 hidden, j>=2 gate
#pragma unroll
    for (int j = 0; j < 4; ++j) {
      const int trow = (j < 2) ? (wn0 + j * 16) : (64 + wn0 + (j - 2) * 16);
      brow[j] = (trow + l15) * 64;
    }
  } else {
    const int wn = (wave & 1) * 64;
#pragma unroll
    for (int j = 0; j < 4; ++j) brow[j] = (wn + j * 16 + l15) * 64;
  }

  // per-job staging addresses (XCD-stable swizzle applied to job index)
  auto addrs = [&](int job, const ushort*& ga, const ushort*& gb) {
    const int id  = (job & 7) * (njobs >> 3) + (job >> 3);
    const int bxi = id % nbx;
    const long bm = (long)(id / nbx) * 128;
    ga = A + (bm + wave * 32 + rl) * (long)KC + cb * 8;
    long bRowBase;
    if (MODE == 1) {
      const long n0 = (long)bxi * 64;
      bRowBase = (wave < 2) ? (n0 + wave * 32) : (1024 + n0 + (wave - 2) * 32);
    } else {
      bRowBase = (long)bxi * 128 + wave * 32;
    }
    gb = Bm + (bRowBase + rl) * (long)KC + cb * 8;
  };

  const ushort *gA0, *gB0;
  addrs(blockIdx.x, gA0, gB0);
  // prologue: stage job0 / k0=0
#pragma unroll
  for (int i = 0; i < 4; ++i) GLDS(gA0 + 8L * i * KC, lA[i]);
#pragma unroll
  for (int i = 0; i < 4; ++i) GLDS(gB0 + 8L * i * KC, lB[i]);

  for (int job = blockIdx.x; job < njobs; job += nblk) {
    const int id  = (job & 7) * (njobs >> 3) + (job >> 3);
    const int bxi = id % nbx;
    const long bm = (long)(id / nbx) * 128;

    f32x4 acc[4][4];
#pragma unroll
    for (int i = 0; i < 4; ++i)
#pragma unroll
      for (int j = 0; j < 4; ++j) acc[i][j] = (f32x4){0.f, 0.f, 0.f, 0.f};

    const ushort *gAn = gA0, *gBn = gB0;

#pragma unroll
    for (int k0 = 0; k0 < KC; k0 += 64) {
      __syncthreads();   // drains vmcnt -> staged tile (k0) ready for all waves

#pragma unroll
      for (int kh = 0; kh < 2; ++kh) {
        const int sq = kh ? sq1 : sq0;
        s16x8 af[4], bf[4];
#pragma unroll
        for (int mi = 0; mi < 4; ++mi)
          af[mi] = *reinterpret_cast<const s16x8*>(&As[arow[mi] + sq]);
#pragma unroll
        for (int ni = 0; ni < 4; ++ni)
          bf[ni] = *reinterpret_cast<const s16x8*>(&Bs[brow[ni] + sq]);
        __builtin_amdgcn_s_setprio(1);
#pragma unroll
        for (int mi = 0; mi < 4; ++mi)
#pragma unroll
          for (int ni = 0; ni < 4; ++ni)
            acc[mi][ni] = mfma_bf16_16x16x32(af[mi], bf[ni], acc[mi][ni]);
        __builtin_amdgcn_s_setprio(0);
      }
      __syncthreads();   // all waves done reading this tile -> LDS free

      if (k0 + 64 < KC) {
        // stage next K-step of current job
#pragma unroll
        for (int i = 0; i < 4; ++i) GLDS(gA0 + 8L * i * KC + (k0 + 64), lA[i]);
#pragma unroll
        for (int i = 0; i < 4; ++i) GLDS(gB0 + 8L * i * KC + (k0 + 64), lB[i]);
      } else {
        // stage NEXT JOB's first K-step; its latency hides under this job's epilogue
        const int nj = job + nblk;
        if (nj < njobs) {
          addrs(nj, gAn, gBn);
#pragma unroll
          for (int i = 0; i < 4; ++i) GLDS(gAn + 8L * i * KC, lA[i]);
#pragma unroll
          for (int i = 0; i < 4; ++i) GLDS(gBn + 8L * i * KC, lB[i]);
        }
      }
    }
    gA0 = gAn; gB0 = gBn;

    // epilogue: C/D layout col = lane&15, row = quad*4 + reg (touches regs/global only)
    if (MODE == 1) {
      const long n0  = (long)bxi * 64;
      const int  wn0 = (wave & 1) * 32;
      // Per 4-row segment (mi, j): transform + store (lc,v); scaled-sum summary
      //   ea = sum lc; em = max_r t_r; es = sum_r exp(t_r - em),  t_r = v_r + suffix_lc.
      float ea[4][2], em[4][2], es[4][2];
#pragma unroll
      for (int mi = 0; mi < 4; ++mi) {
        const long mrow = bm + wm + mi * 16 + quad * 4;
#pragma unroll
        for (int j = 0; j < 2; ++j) {
          const long ch = n0 + wn0 + j * 16 + l15;
          const float bh = bias[ch];
          const float bg = bias[1024 + ch];
          ushort* lp = (ushort*)Cv + mrow * (long)N + ch;
          float lcr[4], vr[4];
#pragma unroll
          for (int r = 0; r < 4; ++r) {
            float hd = acc[mi][j][r] + bh;
            float g  = acc[mi][j + 2][r] + bg;
            transform_f(hd, g, lcr[r], vr[r]);
            lp[(long)r * N] = f2bf(lcr[r]);
            lp[(long)r * N + 1024] = f2bf(vr[r]);
          }
          float run = 0.f, ms = -INFINITY;
          float t0, t1, t2, t3;
          t3 = vr[3];            ms = t3;             run += lcr[3];
          t2 = vr[2] + run;      ms = fmaxf(ms, t2);  run += lcr[2];
          t1 = vr[1] + run;      ms = fmaxf(ms, t1);  run += lcr[1];
          t0 = vr[0] + run;      ms = fmaxf(ms, t0);  run += lcr[0];
          float ss = __expf(t0 - ms) + __expf(t1 - ms) + __expf(t2 - ms) + __expf(t3 - ms);
          ea[mi][j] = run; em[mi][j] = ms; es[mi][j] = ss;
        }
      }
      // chunk combine per (j, cc): chunk = segments (mloc 0,1) x (quad 0..3), L-order
      // p = mloc*16 + quad*4 + r. Suffix lc-sums across quads via 2-step shfl_down scan.
#pragma unroll
      for (int j = 0; j < 2; ++j) {
#pragma unroll
        for (int cc = 0; cc < 2; ++cc) {
          const int mi0 = 2 * cc, mi1 = 2 * cc + 1;
          float suf0 = ea[mi0][j], suf1 = ea[mi1][j];
          { float tt = __shfl_down(suf0, 16); if (quad < 3) suf0 += tt;
            tt = __shfl_down(suf0, 32); if (quad < 2) suf0 += tt; }
          { float tt = __shfl_down(suf1, 16); if (quad < 3) suf1 += tt;
            tt = __shfl_down(suf1, 32); if (quad < 2) suf1 += tt; }
          const float tot0 = __shfl(suf0, l15);   // total lc, mloc 0 (quad0 holds full sum)
          const float tot1 = __shfl(suf1, l15);   // total lc, mloc 1
          // u = segment max + lc-sum of all LATER segments in the chunk
          float u0 = em[mi0][j] + (suf0 - ea[mi0][j]) + tot1;
          float u1 = em[mi1][j] + (suf1 - ea[mi1][j]);
          float Mx = fmaxf(u0, u1);
          Mx = fmaxf(Mx, __shfl_xor(Mx, 16));
          Mx = fmaxf(Mx, __shfl_xor(Mx, 32));
          float contrib = __expf(u0 - Mx) * es[mi0][j] + __expf(u1 - Mx) * es[mi1][j];
          contrib += __shfl_xor(contrib, 16);
          contrib += __shfl_xor(contrib, 32);
          if (quad == 0) {
            const long gc = (bm + wm + cc * 32) >> 5;   // == b*NC_ + c  (L_/32 == NC_)
            const long ch = n0 + wn0 + j * 16 + l15;
            Acp[gc * H_ + ch] = tot0 + tot1;
            Bcp[gc * H_ + ch] = Mx + __logf(contrib);
          }
        }
      }
    } else {
      const int wn = (wave & 1) * 64;
#pragma unroll
      for (int mi = 0; mi < 4; ++mi) {
        const long mrow = bm + wm + mi * 16 + quad * 4;
#pragma unroll
        for (int ni = 0; ni < 4; ++ni) {
          const long ncol = (long)bxi * 128 + wn + ni * 16 + l15;
          const float bv = bias[ncol];
          float* cp = (float*)Cv + mrow * (long)N + ncol;
#pragma unroll
          for (int r = 0; r < 4; ++r) cp[(long)r * N] = acc[mi][ni][r] + bv;
        }
      }
    }
  }
}

// phase 2 (wave-parallel): carry[c] = B-component of the exclusive ∘-scan of chunk pairs.
// One wave per (b,h): lane i composes chunks 4i..4i+3, 6-step shfl_up inclusive scan,
// shift to exclusive, then each lane emits its 4 carries. 1024 blocks (full chip).
__global__ void scan_phase2(const float* __restrict__ Ac, const float* __restrict__ Bc,
                            float* __restrict__ carry) {
  const int wid  = (blockIdx.x * blockDim.x + threadIdx.x) >> 6;  // 0 .. B_*H_-1
  const int lane = threadIdx.x & 63;
  const int h = wid & (H_ - 1);
  const int b = wid >> 10;
  const size_t base = (size_t)b * NC_ * H_ + h;
  float pa[4], pb[4];
#pragma unroll
  for (int k = 0; k < 4; ++k) {
    size_t o = base + (size_t)(4 * lane + k) * H_;
    pa[k] = Ac[o]; pb[k] = Bc[o];
  }
  // local compose (ordered)
  float sA = pa[0], sB = pb[0];
#pragma unroll
  for (int k = 1; k < 4; ++k) { sB = logaddexp_f(sB + pa[k], pb[k]); sA += pa[k]; }
  // inclusive wave scan under ∘ (prev from lower lane is LEFT operand)
  float iA = sA, iB = sB;
#pragma unroll
  for (int d = 1; d < 64; d <<= 1) {
    float uA = __shfl_up(iA, d);
    float uB = __shfl_up(iB, d);
    if (lane >= d) { iB = logaddexp_f(uB + iA, iB); iA = uA + iA; }
  }
  // exclusive
  float eA = __shfl_up(iA, 1);
  float eB = __shfl_up(iB, 1);
  if (lane == 0) { eA = 0.f; eB = -INFINITY; }
  // emit carries for this lane's 4 chunks
  float Bst = eB;
#pragma unroll
  for (int k = 0; k < 4; ++k) {
    size_t o = base + (size_t)(4 * lane + k) * H_;
    carry[o] = Bst;
    Bst = logaddexp_f(Bst + pa[k], pb[k]);
  }
}

// phase 3: re-scan chunk with carry, emit h = exp(log_h) as bf16 (4 channels/thread)
__global__ void scan_phase3(const ushort* __restrict__ hg, const float* __restrict__ carry,
                            ushort* __restrict__ hb) {
  int gid = blockIdx.x * blockDim.x + threadIdx.x;  // B_*NC_*H_/4
  int hq = gid & (H_ / 4 - 1);
  int c  = (gid >> 8) & (NC_ - 1);
  int b  = gid >> 16;
  float4 cr = *reinterpret_cast<const float4*>(&carry[(size_t)(b * NC_ + c) * H_ + hq * 4]);
  float lh[4] = {cr.x, cr.y, cr.z, cr.w};
  const ushort* p = hg + ((size_t)(b * L_ + c * LC_) * (2 * H_)) + hq * 4;
  ushort* q = hb + (size_t)(b * L_ + c * LC_) * H_ + hq * 4;
#pragma unroll 4
  for (int l = 0; l < LC_; ++l) {
    ushort4 lc4 = *reinterpret_cast<const ushort4*>(p);
    ushort4 v4  = *reinterpret_cast<const ushort4*>(p + H_);
    float lcv[4] = {bf2f(lc4.x), bf2f(lc4.y), bf2f(lc4.z), bf2f(lc4.w)};
    float vv[4]  = {bf2f(v4.x),  bf2f(v4.y),  bf2f(v4.z),  bf2f(v4.w)};
    ushort4 o;
    ushort* op = &o.x;
#pragma unroll
    for (int j = 0; j < 4; ++j) {
      lh[j] = logaddexp_f(lh[j] + lcv[j], vv[j]);
      op[j] = f2bf(__expf(lh[j]));
    }
    *reinterpret_cast<ushort4*>(q) = o;
    p += 2 * H_;
    q += H_;
  }
}

extern "C" void kernel_launch(void* const* d_in, const int* in_sizes, int n_in,
                              void* d_out, int out_size, void* d_ws, size_t ws_size,
                              hipStream_t stream) {
  const float* x     = (const float*)d_in[0];
  const float* W_in  = (const float*)d_in[1];
  const float* b_in  = (const float*)d_in[2];
  const float* W_out = (const float*)d_in[3];
  const float* b_out = (const float*)d_in[4];
  float* out = (float*)d_out;

  char* ws = (char*)d_ws;
  size_t off = 0;
  auto alloc = [&](size_t bytes) {
    void* p = ws + off;
    off = (off + bytes + 255) & ~(size_t)255;
    return p;
  };
  // region shared by xb (alive: cast -> GEMM1) and hb (alive: phase3 -> GEMM2)
  ushort* xb    = (ushort*)alloc((size_t)B_ * L_ * H_ * 2);       // 67 MB (union)
  ushort* hb    = xb;
  ushort* Wib   = (ushort*)alloc((size_t)2 * H_ * D_ * 2);        // 2 MB
  ushort* Wob   = (ushort*)alloc((size_t)D_ * H_ * 2);            // 1 MB
  ushort* hgb   = (ushort*)alloc((size_t)B_ * L_ * 2 * H_ * 2);   // 134 MB (bf16: lc, v)
  float*  Ac    = (float*)alloc((size_t)B_ * NC_ * H_ * 4);       // 4 MB
  float*  Bc    = (float*)alloc((size_t)B_ * NC_ * H_ * 4);       // 4 MB
  float*  carry = (float*)alloc((size_t)B_ * NC_ * H_ * 4);       // 4 MB
  // total ~216 MB

  // one merged cast launch: x, W_in, W_out
  {
    int n0 = B_ * L_ * D_ / 4, n1 = 2 * H_ * D_ / 4, n2 = D_ * H_ / 4;
    cast3_kernel<<<(n0 + n1 + n2 + 255) / 256, 256, 0, stream>>>(
        x, xb, n0, W_in, Wib, n1, W_out, Wob, n2);
  }

  // GEMM1 (persistent): (lc, v) = transform(x . W_in^T + b_in)  AND chunk summaries
  // jobs = 16 x 256 = 4096 tiles; 768 blocks = 3/CU.
  gemm_bt<1, 512><<<768, 256, 0, stream>>>(
      xb, Wib, b_in, hgb, Ac, Bc, B_ * L_, 2 * H_, 16, 4096);

  // exclusive scan over chunk summaries -> carries (one wave per (b,h))
  scan_phase2<<<(B_ * H_ * 64) / 256, 256, 0, stream>>>(Ac, Bc, carry);
  // re-scan chunks with carry, emit h (bf16)
  scan_phase3<<<(B_ * NC_ * H_ / 4) / 256, 256, 0, stream>>>(hgb, carry, hb);

  // GEMM2 (persistent): out = h . W_out^T + b_out; jobs = 4 x 256 = 1024 tiles.
  gemm_bt<0, 1024><<<768, 256, 0, stream>>>(
      hb, Wob, b_out, out, nullptr, nullptr, B_ * L_, D_, 4, 1024);
}